// Round 1
// 1086.151 us; speedup vs baseline: 1.3147x; 1.3147x over previous
//
#include <hip/hip_runtime.h>
#include <cstdint>
#include <cstddef>

#define M_ROWS 32768   // B*N
#define CDIM   512
#define KRANK  150
#define KPAD   160     // padded rank for MFMA (zeros beyond 150)

typedef __bf16 bf16x8 __attribute__((ext_vector_type(8)));
typedef float  f32x4  __attribute__((ext_vector_type(4)));

union U16B { uint4 u; bf16x8 b; };
static __device__ __forceinline__ bf16x8 u2b(uint4 u) { U16B x; x.u = u; return x.b; }

static __device__ __forceinline__ unsigned short f2bf(float f) {
  uint32_t u = __float_as_uint(f);
  u += 0x7fffu + ((u >> 16) & 1u);
  return (unsigned short)(u >> 16);
}

// split 8 fp32 into hi/lo bf16 (hi = RNE(v), lo = RNE(v - hi)); err ~2^-16 rel
static __device__ __forceinline__ void cvt8(float4 a, float4 b, uint4& h, uint4& l) {
  float v[8] = {a.x, a.y, a.z, a.w, b.x, b.y, b.z, b.w};
  unsigned short hs[8], ls[8];
#pragma unroll
  for (int i = 0; i < 8; ++i) {
    hs[i] = f2bf(v[i]);
    const float hf = __uint_as_float((uint32_t)hs[i] << 16);
    ls[i] = f2bf(v[i] - hf);
  }
  h = *(uint4*)&hs[0];
  l = *(uint4*)&ls[0];
}

// ================= legacy fp32 GEMM: out[m][n] = sum_k X[m][k]*W[n][k] + bias[n] ======
// MODE 2: Q: fp32 out (stride ostride) + aux = packed hi/lo bf16 [m][320] (cols>=150 zero)
// MODE 3: K: aux packed hi/lo bf16 only
template<int MODE>
__global__ __launch_bounds__(256)
void gemm_nt(const float* __restrict__ X, const float* __restrict__ W,
             const float* __restrict__ bias, float* __restrict__ out,
             int N, int ostride,
             const float* __restrict__ xres, const float* __restrict__ gammap,
             unsigned short* __restrict__ aux)
{
  __shared__ __align__(16) float as[16][132];
  __shared__ __align__(16) float bs[16][132];
  const int m0 = blockIdx.y * 128;
  const int n0 = blockIdx.x * 128;
  const int tid = threadIdx.x;
  const int tx = tid & 15, ty = tid >> 4;

  float acc[8][8];
#pragma unroll
  for (int i = 0; i < 8; ++i)
#pragma unroll
    for (int j = 0; j < 8; ++j) acc[i][j] = 0.f;

  for (int kt = 0; kt < 512; kt += 16) {
#pragma unroll
    for (int h = 0; h < 2; ++h) {
      const int f4 = tid + h * 256;      // 0..511
      const int row = f4 >> 2;           // 0..127
      const int kc = (f4 & 3) * 4;       // 0,4,8,12
      const float4 v = *(const float4*)&X[(size_t)(m0 + row) * 512 + kt + kc];
      as[kc + 0][row] = v.x; as[kc + 1][row] = v.y;
      as[kc + 2][row] = v.z; as[kc + 3][row] = v.w;
      const int wrow = n0 + row;
      float4 wv = make_float4(0.f, 0.f, 0.f, 0.f);
      if (wrow < N) wv = *(const float4*)&W[(size_t)wrow * 512 + kt + kc];
      bs[kc + 0][row] = wv.x; bs[kc + 1][row] = wv.y;
      bs[kc + 2][row] = wv.z; bs[kc + 3][row] = wv.w;
    }
    __syncthreads();
#pragma unroll 4
    for (int k = 0; k < 16; ++k) {
      float a[8], b[8];
      *(float4*)&a[0] = *(const float4*)&as[k][ty * 8];
      *(float4*)&a[4] = *(const float4*)&as[k][ty * 8 + 4];
      *(float4*)&b[0] = *(const float4*)&bs[k][tx * 8];
      *(float4*)&b[4] = *(const float4*)&bs[k][tx * 8 + 4];
#pragma unroll
      for (int i = 0; i < 8; ++i)
#pragma unroll
        for (int j = 0; j < 8; ++j)
          acc[i][j] = fmaf(a[i], b[j], acc[i][j]);
    }
    __syncthreads();
  }

  float bvv[8];
#pragma unroll
  for (int j = 0; j < 8; ++j) {
    const int n = n0 + tx * 8 + j;
    bvv[j] = (n < N) ? bias[n] : 0.f;
  }
  const int nb = n0 + tx * 8;

#pragma unroll
  for (int i = 0; i < 8; ++i) {
    const int m = m0 + ty * 8 + i;
    float vals[8];
#pragma unroll
    for (int j = 0; j < 8; ++j) vals[j] = acc[i][j] + bvv[j];

    {  // MODE 2 / 3
      unsigned short hi8[8], lo8[8];
#pragma unroll
      for (int j = 0; j < 8; ++j) {
        const int n = nb + j;
        float v = (n < KRANK) ? vals[j] : 0.f;
        if (MODE == 2 && n < KRANK) out[(size_t)m * ostride + n] = v;
        const unsigned short h = f2bf(v);
        hi8[j] = h;
        const float hf = __uint_as_float(((uint32_t)h) << 16);
        lo8[j] = f2bf(v - hf);
      }
      if (nb < KPAD) {
        *(uint4*)&aux[(size_t)m * 320 + nb]       = *(uint4*)&hi8[0];
        *(uint4*)&aux[(size_t)m * 320 + 160 + nb] = *(uint4*)&lo8[0];
      }
    }
  }
}

// ================= MFMA hi/lo GEMM (fp32-accurate via 3-product bf16) =================
// out[m][n] = sum_k A[m][k]*W[n][k] (+bias).  M=32768, N=512, K=512.
// Tile: 128m x 256n per block, 8 waves (2m x 4n), wave tile 64x64 = 4x4 16x16 frags.
// K-step 32. LDS pair-swizzled at 16B-cell granularity:
//   addr16(row,k4) = (row>>1)*8 + (((row&1)*4 + k4) ^ ((row>>1)&7))
// -> conflict-free for both staging writes (tid-linear cells) and fragment reads
//    (row = cq varies per lane, k4 = quad).
// MODE 4: VT output bf16 [b][col][4096] (+bias).  MODE 1: out = gamma*(acc+bias)+xres.
template<int MODE>
__global__ __launch_bounds__(512, 4)
void mgemm_nt(const float* __restrict__ A, const float* __restrict__ W,
              const float* __restrict__ bias, float* __restrict__ out,
              const float* __restrict__ xres, const float* __restrict__ gammap,
              unsigned short* __restrict__ VT)
{
  // regions (ushort offsets): AH 0 (4096), AL 4096, BH 8192 (8192), BL 16384. 49152 B.
  __shared__ __align__(16) unsigned short lds[24576];
  const int tid = threadIdx.x;
  const int m0  = blockIdx.y * 128;
  const int n0b = blockIdx.x * 256;

  // ---- staging geometry: A = 512 cells (1/thread), B = 1024 cells (2/thread) ----
  const int srow = tid >> 2, sk4 = tid & 3;
  const int sa16 = ((srow >> 1) << 3) + ((((srow & 1) << 2) | sk4) ^ ((srow >> 1) & 7));
  const float* ap  = A + (size_t)(m0 + srow) * 512 + sk4 * 8;
  const float* bp0 = W + (size_t)(n0b + srow) * 512 + sk4 * 8;
  const float* bp1 = W + (size_t)(n0b + 128 + srow) * 512 + sk4 * 8;

  // ---- fragment geometry (same lane mapping as attn S-phase, verified) ----
  const int lane = tid & 63, w = tid >> 6;
  const int wm = w >> 2, wn = w & 3;
  const int cq = lane & 15, quad = lane >> 4;
  const int fsub = (((cq & 1) << 2) | quad) ^ (cq >> 1);
  const int a16 = wm * 256 + ((cq >> 1) << 3) + fsub;   // + i*64 cells
  const int b16 = wn * 256 + ((cq >> 1) << 3) + fsub;   // + j*64 cells

  f32x4 acc[4][4];
#pragma unroll
  for (int i = 0; i < 4; ++i)
#pragma unroll
    for (int j = 0; j < 4; ++j) acc[i][j] = (f32x4){0.f, 0.f, 0.f, 0.f};

  for (int kt = 0; kt < 512; kt += 32) {
    // load + convert next K-slab (overlaps other waves' tail compute / barrier wait)
    const float4 av0 = *(const float4*)(ap + kt);
    const float4 av1 = *(const float4*)(ap + kt + 4);
    const float4 bv0 = *(const float4*)(bp0 + kt);
    const float4 bv1 = *(const float4*)(bp0 + kt + 4);
    const float4 cv0 = *(const float4*)(bp1 + kt);
    const float4 cv1 = *(const float4*)(bp1 + kt + 4);
    uint4 ahi, alo, bhi, blo, chi, clo;
    cvt8(av0, av1, ahi, alo);
    cvt8(bv0, bv1, bhi, blo);
    cvt8(cv0, cv1, chi, clo);

    __syncthreads();   // A: previous tile's readers done
    *(uint4*)&lds[        sa16 * 8]        = ahi;
    *(uint4*)&lds[4096  + sa16 * 8]        = alo;
    *(uint4*)&lds[8192  + sa16 * 8]        = bhi;
    *(uint4*)&lds[16384 + sa16 * 8]        = blo;
    *(uint4*)&lds[8192  + sa16 * 8 + 4096] = chi;   // B rows 128..255
    *(uint4*)&lds[16384 + sa16 * 8 + 4096] = clo;
    __syncthreads();   // B: staging visible

    bf16x8 ah[4], al_[4];
#pragma unroll
    for (int i = 0; i < 4; ++i) {
      ah[i]  = u2b(*(const uint4*)&lds[       (a16 + i * 64) * 8]);
      al_[i] = u2b(*(const uint4*)&lds[4096 + (a16 + i * 64) * 8]);
    }
#pragma unroll
    for (int j = 0; j < 4; ++j) {
      const bf16x8 bh = u2b(*(const uint4*)&lds[8192  + (b16 + j * 64) * 8]);
      const bf16x8 bl = u2b(*(const uint4*)&lds[16384 + (b16 + j * 64) * 8]);
#pragma unroll
      for (int i = 0; i < 4; ++i) {
        acc[i][j] = __builtin_amdgcn_mfma_f32_16x16x32_bf16(ah[i],  bh, acc[i][j], 0, 0, 0);
        acc[i][j] = __builtin_amdgcn_mfma_f32_16x16x32_bf16(al_[i], bh, acc[i][j], 0, 0, 0);
        acc[i][j] = __builtin_amdgcn_mfma_f32_16x16x32_bf16(ah[i],  bl, acc[i][j], 0, 0, 0);
      }
    }
  }

  // ---- epilogue: C frag elem (i,j,r): m = m0+wm*64+i*16+quad*4+r, n = n0b+wn*64+j*16+cq
  const int mb = m0 + wm * 64 + quad * 4;
  const int nb = n0b + wn * 64 + cq;

  if (MODE == 1) {
    const float g = gammap[0];
#pragma unroll
    for (int j = 0; j < 4; ++j) {
      const float bvj = bias[nb + j * 16];
#pragma unroll
      for (int i = 0; i < 4; ++i) {
#pragma unroll
        for (int r = 0; r < 4; ++r) {
          const size_t off = (size_t)(mb + i * 16 + r) * 512 + (nb + j * 16);
          out[off] = fmaf(g, acc[i][j][r] + bvj, xres[off]);
        }
      }
    }
  } else {  // MODE 4: VT[b][n][key] bf16
    const int b = m0 >> 12;
    const int key0 = (m0 & 4095) + wm * 64 + quad * 4;
#pragma unroll
    for (int j = 0; j < 4; ++j) {
      const float bvj = bias[nb + j * 16];
      const size_t rowo = (size_t)(b * 512 + nb + j * 16) * 4096;
#pragma unroll
      for (int i = 0; i < 4; ++i) {
        unsigned short o4[4];
#pragma unroll
        for (int r = 0; r < 4; ++r) o4[r] = f2bf(acc[i][j][r] + bvj);
        uint2 o;
        o.x = (unsigned int)o4[0] | ((unsigned int)o4[1] << 16);
        o.y = (unsigned int)o4[2] | ((unsigned int)o4[3] << 16);
        *(uint2*)&VT[rowo + key0 + i * 16] = o;
      }
    }
  }
}

// ================= MFMA flash attention (v5) =================
// 512 blocks: b = bid&7 (XCD-affine), ch = (bid>>3)&1 (256-col half), qt = bid>>4.
// 512 threads = 8 waves; wave w owns q-rows [w*16, w*16+16) x this col-half for S AND PV
// (everything wave-private, 2 barriers/iter). Register prefetch issued post-barrier-B
// so global loads are in flight for the whole compute phase.
__global__ __launch_bounds__(512, 2)
void attn_mfma(const unsigned short* __restrict__ Qc,   // [32768][320] hi|lo
               const unsigned short* __restrict__ Kc,   // [32768][320] hi|lo
               const unsigned short* __restrict__ VT,   // [8][512][4096] bf16
               float* __restrict__ O)                   // [32768][512] fp32
{
  // klds 32x328 (10496) + vtl 256x40 (10240) + plds 8x(16x40) (5120) = 25856 ush = 51712 B
  __shared__ __align__(16) unsigned short smem[25856];
  unsigned short* klds = smem;              // 32 keys x 328 (320 data + 8 pad)
  unsigned short* vtl  = smem + 10496;      // 256 cols x 40 (32 keys + 8 pad)
  unsigned short* plds = smem + 20736;      // per-wave 16 rows x 40

  const int bid = blockIdx.x;
  const int b   = bid & 7;                  // XCD-affine batch
  const int ch  = (bid >> 3) & 1;
  const int qt  = bid >> 4;                 // 0..31
  const int r0  = (b << 12) + qt * 128;
  const int cb0 = ch * 256;

  const int tid  = threadIdx.x;             // 0..511
  const int w    = tid >> 6;                // 0..7
  const int lane = tid & 63;
  const int quad = lane >> 4;
  const int cq   = lane & 15;

  // ---- persistent Q fragments (A-operand layout), rows r0 + w*16 + cq ----
  bf16x8 qhi[5], qlo[5];
  {
    const size_t qrow = (size_t)(r0 + w * 16 + cq) * 320;
#pragma unroll
    for (int c = 0; c < 5; ++c) {
      qhi[c] = u2b(*(const uint4*)(Qc + qrow + c * 32 + quad * 8));
      qlo[c] = u2b(*(const uint4*)(Qc + qrow + 160 + c * 32 + quad * 8));
    }
  }

  f32x4 acc4[16];
#pragma unroll
  for (int i = 0; i < 16; ++i) acc4[i] = (f32x4){0.f, 0.f, 0.f, 0.f};
  float mreg[4], lreg[4];
#pragma unroll
  for (int r = 0; r < 4; ++r) { mreg[r] = -3.0e38f; lreg[r] = 0.f; }

  const int vqd = (tid & 3) * 8;        // V key sub-offset (8 ushorts)
  const int vc  = tid >> 2;             // 0..127 column group

  // K staging geometry (1280 uint4 cells): p = tid, tid+512, (tid<256: tid+1024)
  const int krow0 = tid / 40,          kc0 = (tid - krow0 * 40) * 8;
  const int krow1 = (tid + 512) / 40,  kc1 = ((tid + 512) - krow1 * 40) * 8;
  const int krow2 = (tid + 1024) / 40, kc2 = ((tid + 1024) - krow2 * 40) * 8;

  uint4 pk0, pk1, pk2, pv0, pv1;
  // ---- initial prefetch (tile 0) ----
  {
    const unsigned short* kb_p = Kc + (size_t)(b * 4096) * 320;
    pk0 = *(const uint4*)(kb_p + (size_t)tid * 8);
    pk1 = *(const uint4*)(kb_p + (size_t)(tid + 512) * 8);
    if (tid < 256) pk2 = *(const uint4*)(kb_p + (size_t)(tid + 1024) * 8);
    const unsigned short* vb_p = VT + ((size_t)(b * 512 + cb0 + vc)) * 4096 + vqd;
    pv0 = *(const uint4*)(vb_p);
    pv1 = *(const uint4*)(vb_p + (size_t)128 * 4096);
  }

  for (int kt = 0; kt < 128; ++kt) {
    __syncthreads();  // A: previous tile's LDS readers done; drains prefetch loads

    // ---- stage prefetched K / V tiles into LDS ----
    *(uint4*)&klds[krow0 * 328 + kc0] = pk0;
    *(uint4*)&klds[krow1 * 328 + kc1] = pk1;
    if (tid < 256) *(uint4*)&klds[krow2 * 328 + kc2] = pk2;
    *(uint4*)&vtl[vc * 40 + vqd] = pv0;
    *(uint4*)&vtl[(vc + 128) * 40 + vqd] = pv1;

    __syncthreads();  // B: staging visible

    // ---- issue prefetch for next tile (in flight during S+softmax+PV) ----
    {
      const int ktn = (kt < 127) ? kt + 1 : 127;
      const unsigned short* kb_p = Kc + (size_t)(b * 4096 + ktn * 32) * 320;
      pk0 = *(const uint4*)(kb_p + (size_t)tid * 8);
      pk1 = *(const uint4*)(kb_p + (size_t)(tid + 512) * 8);
      if (tid < 256) pk2 = *(const uint4*)(kb_p + (size_t)(tid + 1024) * 8);
      const unsigned short* vb_p = VT + ((size_t)(b * 512 + cb0 + vc)) * 4096 + ktn * 32 + vqd;
      pv0 = *(const uint4*)(vb_p);
      pv1 = *(const uint4*)(vb_p + (size_t)128 * 4096);
    }

    // ---- S phase: wave w -> rows [w*16, w*16+16) x 32 keys ----
    f32x4 S0 = (f32x4){0.f, 0.f, 0.f, 0.f};
    f32x4 S1 = (f32x4){0.f, 0.f, 0.f, 0.f};
#pragma unroll
    for (int c = 0; c < 5; ++c) {
      const int ko = c * 32 + quad * 8;
      const bf16x8 kh0 = u2b(*(const uint4*)&klds[cq * 328 + ko]);
      const bf16x8 kl0 = u2b(*(const uint4*)&klds[cq * 328 + 160 + ko]);
      const bf16x8 kh1 = u2b(*(const uint4*)&klds[(16 + cq) * 328 + ko]);
      const bf16x8 kl1 = u2b(*(const uint4*)&klds[(16 + cq) * 328 + 160 + ko]);
      S0 = __builtin_amdgcn_mfma_f32_16x16x32_bf16(qhi[c], kh0, S0, 0, 0, 0);
      S1 = __builtin_amdgcn_mfma_f32_16x16x32_bf16(qhi[c], kh1, S1, 0, 0, 0);
      S0 = __builtin_amdgcn_mfma_f32_16x16x32_bf16(qhi[c], kl0, S0, 0, 0, 0);
      S1 = __builtin_amdgcn_mfma_f32_16x16x32_bf16(qhi[c], kl1, S1, 0, 0, 0);
      S0 = __builtin_amdgcn_mfma_f32_16x16x32_bf16(qlo[c], kh0, S0, 0, 0, 0);
      S1 = __builtin_amdgcn_mfma_f32_16x16x32_bf16(qlo[c], kh1, S1, 0, 0, 0);
    }

    // ---- wave-local online softmax (row = quad*4+r, keys cq / 16+cq) ----
    unsigned short* pw = plds + w * 640;
    float alph[4];
    bool upd = false;
#pragma unroll
    for (int r = 0; r < 4; ++r) {
      const float s0 = S0[r], s1 = S1[r];
      float t = fmaxf(s0, s1);
      t = fmaxf(t, __shfl_xor(t, 1));
      t = fmaxf(t, __shfl_xor(t, 2));
      t = fmaxf(t, __shfl_xor(t, 4));
      t = fmaxf(t, __shfl_xor(t, 8));
      const float mo = mreg[r];
      const float mn = fmaxf(mo, t);
      upd = upd || (mn > mo);
      const float al = __expf(mo - mn);
      const float p0 = __expf(s0 - mn);
      const float p1 = __expf(s1 - mn);
      float ts = p0 + p1;
      ts += __shfl_xor(ts, 1);
      ts += __shfl_xor(ts, 2);
      ts += __shfl_xor(ts, 4);
      ts += __shfl_xor(ts, 8);
      lreg[r] = lreg[r] * al + ts;
      mreg[r] = mn;
      alph[r] = al;
      const int prow = (quad * 4 + r) * 40;
      pw[prow + cq]      = f2bf(p0);
      pw[prow + 16 + cq] = f2bf(p1);
    }

    if (__any(upd)) {
#pragma unroll
      for (int i = 0; i < 16; ++i) {
        acc4[i][0] *= alph[0]; acc4[i][1] *= alph[1];
        acc4[i][2] *= alph[2]; acc4[i][3] *= alph[3];
      }
    }

    // ---- PV phase (wave-local): rows [w*16..) x cols [cb0, cb0+256) ----
    const bf16x8 pa = u2b(*(const uint4*)&pw[cq * 40 + quad * 8]);
#pragma unroll
    for (int i = 0; i < 16; ++i) {
      const bf16x8 vb = u2b(*(const uint4*)&vtl[(i * 16 + cq) * 40 + quad * 8]);
      acc4[i] = __builtin_amdgcn_mfma_f32_16x16x32_bf16(pa, vb, acc4[i], 0, 0, 0);
    }
  }

  // ---- epilogue: O = acc/l, staged through LDS (64-col quarters) ----
  float inv[4];
#pragma unroll
  for (int r = 0; r < 4; ++r) inv[r] = 1.f / lreg[r];

  __syncthreads();  // all waves done with klds/vtl before overlay
  float* ep = (float*)smem + w * 1088;     // 16 rows x 68 fp32 per wave (4352 B)
  const int r0w = r0 + w * 16;
#pragma unroll
  for (int qtr = 0; qtr < 4; ++qtr) {
#pragma unroll
    for (int ii = 0; ii < 4; ++ii)
#pragma unroll
      for (int r = 0; r < 4; ++r)
        ep[(quad * 4 + r) * 68 + ii * 16 + cq] = acc4[qtr * 4 + ii][r] * inv[r];
    // wave-private RAW; ds ops complete in order per wave
#pragma unroll
    for (int t = 0; t < 4; ++t) {
      const int flat4 = t * 64 + lane;     // 0..255 float4 units (16 rows x 16)
      const int row = flat4 >> 4;          // 0..15
      const int c4 = flat4 & 15;
      const float4 val = *(const float4*)&ep[row * 68 + c4 * 4];
      *(float4*)&O[(size_t)(r0w + row) * CDIM + cb0 + qtr * 64 + c4 * 4] = val;
    }
  }
}

extern "C" void kernel_launch(void* const* d_in, const int* in_sizes, int n_in,
                              void* d_out, int out_size, void* d_ws, size_t ws_size,
                              hipStream_t stream)
{
  const float* x     = (const float*)d_in[0];
  const float* Wq    = (const float*)d_in[1];
  const float* bq    = (const float*)d_in[2];
  const float* Wk    = (const float*)d_in[3];
  const float* bk    = (const float*)d_in[4];
  const float* Wv    = (const float*)d_in[5];
  const float* bv    = (const float*)d_in[6];
  const float* Wres  = (const float*)d_in[7];
  const float* bres  = (const float*)d_in[8];
  const float* gamma = (const float*)d_in[9];

  float* seg_map  = (float*)d_out;                         // 32768 x 150
  float* feat_map = seg_map + (size_t)M_ROWS * KRANK;      // 32768 x 512

  unsigned short* Qcomb = (unsigned short*)d_ws;                       // [32768][320]
  unsigned short* Kcomb = Qcomb + (size_t)M_ROWS * 320;                // [32768][320]
  unsigned short* VTb   = Kcomb + (size_t)M_ROWS * 320;                // [8][512][4096]
  float*          feats = (float*)(VTb + (size_t)M_ROWS * CDIM);       // [32768][512]

  dim3 blk(256);
  gemm_nt<2><<<dim3(2, 256), blk, 0, stream>>>(x, Wq, bq, seg_map, KRANK, KRANK, nullptr, nullptr, Qcomb);
  gemm_nt<3><<<dim3(2, 256), blk, 0, stream>>>(x, Wk, bk, nullptr,  KRANK, KRANK, nullptr, nullptr, Kcomb);
  mgemm_nt<4><<<dim3(2, 256), dim3(512), 0, stream>>>(x, Wv, bv, nullptr, nullptr, nullptr, VTb);
  attn_mfma<<<dim3(512), dim3(512), 0, stream>>>(Qcomb, Kcomb, VTb, feats);
  mgemm_nt<1><<<dim3(2, 256), dim3(512), 0, stream>>>(feats, Wres, bres, feat_map, x, gamma, nullptr);
}

// Round 2
// 884.012 us; speedup vs baseline: 1.6153x; 1.2287x over previous
//
#include <hip/hip_runtime.h>
#include <cstdint>
#include <cstddef>

#define M_ROWS 32768   // B*N
#define CDIM   512
#define KRANK  150
#define KPAD   160     // padded rank for MFMA (zeros beyond 150)

typedef __bf16 bf16x8 __attribute__((ext_vector_type(8)));
typedef float  f32x4  __attribute__((ext_vector_type(4)));

union U16B { uint4 u; bf16x8 b; };
static __device__ __forceinline__ bf16x8 u2b(uint4 u) { U16B x; x.u = u; return x.b; }

static __device__ __forceinline__ unsigned short f2bf(float f) {
  uint32_t u = __float_as_uint(f);
  u += 0x7fffu + ((u >> 16) & 1u);
  return (unsigned short)(u >> 16);
}

// split 8 fp32 into hi/lo bf16 (hi = RNE(v), lo = RNE(v - hi)); err ~2^-16 rel
static __device__ __forceinline__ void cvt8(float4 a, float4 b, uint4& h, uint4& l) {
  float v[8] = {a.x, a.y, a.z, a.w, b.x, b.y, b.z, b.w};
  unsigned short hs[8], ls[8];
#pragma unroll
  for (int i = 0; i < 8; ++i) {
    hs[i] = f2bf(v[i]);
    const float hf = __uint_as_float((uint32_t)hs[i] << 16);
    ls[i] = f2bf(v[i] - hf);
  }
  h = *(uint4*)&hs[0];
  l = *(uint4*)&ls[0];
}

// ================= legacy fp32 GEMM: out[m][n] = sum_k X[m][k]*W[n][k] + bias[n] ======
// MODE 2: Q: fp32 out (stride ostride) + aux = packed hi/lo bf16 [m][320] (cols>=150 zero)
// MODE 3: K: aux packed hi/lo bf16 only
template<int MODE>
__global__ __launch_bounds__(256)
void gemm_nt(const float* __restrict__ X, const float* __restrict__ W,
             const float* __restrict__ bias, float* __restrict__ out,
             int N, int ostride,
             const float* __restrict__ xres, const float* __restrict__ gammap,
             unsigned short* __restrict__ aux)
{
  __shared__ __align__(16) float as[16][132];
  __shared__ __align__(16) float bs[16][132];
  const int m0 = blockIdx.y * 128;
  const int n0 = blockIdx.x * 128;
  const int tid = threadIdx.x;
  const int tx = tid & 15, ty = tid >> 4;

  float acc[8][8];
#pragma unroll
  for (int i = 0; i < 8; ++i)
#pragma unroll
    for (int j = 0; j < 8; ++j) acc[i][j] = 0.f;

  for (int kt = 0; kt < 512; kt += 16) {
#pragma unroll
    for (int h = 0; h < 2; ++h) {
      const int f4 = tid + h * 256;      // 0..511
      const int row = f4 >> 2;           // 0..127
      const int kc = (f4 & 3) * 4;       // 0,4,8,12
      const float4 v = *(const float4*)&X[(size_t)(m0 + row) * 512 + kt + kc];
      as[kc + 0][row] = v.x; as[kc + 1][row] = v.y;
      as[kc + 2][row] = v.z; as[kc + 3][row] = v.w;
      const int wrow = n0 + row;
      float4 wv = make_float4(0.f, 0.f, 0.f, 0.f);
      if (wrow < N) wv = *(const float4*)&W[(size_t)wrow * 512 + kt + kc];
      bs[kc + 0][row] = wv.x; bs[kc + 1][row] = wv.y;
      bs[kc + 2][row] = wv.z; bs[kc + 3][row] = wv.w;
    }
    __syncthreads();
#pragma unroll 4
    for (int k = 0; k < 16; ++k) {
      float a[8], b[8];
      *(float4*)&a[0] = *(const float4*)&as[k][ty * 8];
      *(float4*)&a[4] = *(const float4*)&as[k][ty * 8 + 4];
      *(float4*)&b[0] = *(const float4*)&bs[k][tx * 8];
      *(float4*)&b[4] = *(const float4*)&bs[k][tx * 8 + 4];
#pragma unroll
      for (int i = 0; i < 8; ++i)
#pragma unroll
        for (int j = 0; j < 8; ++j)
          acc[i][j] = fmaf(a[i], b[j], acc[i][j]);
    }
    __syncthreads();
  }

  float bvv[8];
#pragma unroll
  for (int j = 0; j < 8; ++j) {
    const int n = n0 + tx * 8 + j;
    bvv[j] = (n < N) ? bias[n] : 0.f;
  }
  const int nb = n0 + tx * 8;

#pragma unroll
  for (int i = 0; i < 8; ++i) {
    const int m = m0 + ty * 8 + i;
    float vals[8];
#pragma unroll
    for (int j = 0; j < 8; ++j) vals[j] = acc[i][j] + bvv[j];

    {  // MODE 2 / 3
      unsigned short hi8[8], lo8[8];
#pragma unroll
      for (int j = 0; j < 8; ++j) {
        const int n = nb + j;
        float v = (n < KRANK) ? vals[j] : 0.f;
        if (MODE == 2 && n < KRANK) out[(size_t)m * ostride + n] = v;
        const unsigned short h = f2bf(v);
        hi8[j] = h;
        const float hf = __uint_as_float(((uint32_t)h) << 16);
        lo8[j] = f2bf(v - hf);
      }
      if (nb < KPAD) {
        *(uint4*)&aux[(size_t)m * 320 + nb]       = *(uint4*)&hi8[0];
        *(uint4*)&aux[(size_t)m * 320 + 160 + nb] = *(uint4*)&lo8[0];
      }
    }
  }
}

// ================= MFMA hi/lo GEMM (fp32-accurate via 3-product bf16) =================
// out[m][n] = sum_k A[m][k]*W[n][k] (+bias).  M=32768, N=512, K=512.
// Tile: 128m x 256n per block, 8 waves (2m x 4n), wave tile 64x64 = 4x4 16x16 frags.
// K-step 32. LDS pair-swizzled at 16B-cell granularity:
//   addr16(row,k4) = (row>>1)*8 + (((row&1)*4 + k4) ^ ((row>>1)&7))
// MODE 4: VT output bf16 [b][col][4096] (+bias).  MODE 1: out = gamma*(acc+bias)+xres.
template<int MODE>
__global__ __launch_bounds__(512, 4)
void mgemm_nt(const float* __restrict__ A, const float* __restrict__ W,
              const float* __restrict__ bias, float* __restrict__ out,
              const float* __restrict__ xres, const float* __restrict__ gammap,
              unsigned short* __restrict__ VT)
{
  // regions (ushort offsets): AH 0 (4096), AL 4096, BH 8192 (8192), BL 16384. 49152 B.
  __shared__ __align__(16) unsigned short lds[24576];
  const int tid = threadIdx.x;
  const int m0  = blockIdx.y * 128;
  const int n0b = blockIdx.x * 256;

  // ---- staging geometry: A = 512 cells (1/thread), B = 1024 cells (2/thread) ----
  const int srow = tid >> 2, sk4 = tid & 3;
  const int sa16 = ((srow >> 1) << 3) + ((((srow & 1) << 2) | sk4) ^ ((srow >> 1) & 7));
  const float* ap  = A + (size_t)(m0 + srow) * 512 + sk4 * 8;
  const float* bp0 = W + (size_t)(n0b + srow) * 512 + sk4 * 8;
  const float* bp1 = W + (size_t)(n0b + 128 + srow) * 512 + sk4 * 8;

  // ---- fragment geometry ----
  const int lane = tid & 63, w = tid >> 6;
  const int wm = w >> 2, wn = w & 3;
  const int cq = lane & 15, quad = lane >> 4;
  const int fsub = (((cq & 1) << 2) | quad) ^ (cq >> 1);
  const int a16 = wm * 256 + ((cq >> 1) << 3) + fsub;   // + i*64 cells
  const int b16 = wn * 256 + ((cq >> 1) << 3) + fsub;   // + j*64 cells

  f32x4 acc[4][4];
#pragma unroll
  for (int i = 0; i < 4; ++i)
#pragma unroll
    for (int j = 0; j < 4; ++j) acc[i][j] = (f32x4){0.f, 0.f, 0.f, 0.f};

  for (int kt = 0; kt < 512; kt += 32) {
    const float4 av0 = *(const float4*)(ap + kt);
    const float4 av1 = *(const float4*)(ap + kt + 4);
    const float4 bv0 = *(const float4*)(bp0 + kt);
    const float4 bv1 = *(const float4*)(bp0 + kt + 4);
    const float4 cv0 = *(const float4*)(bp1 + kt);
    const float4 cv1 = *(const float4*)(bp1 + kt + 4);
    uint4 ahi, alo, bhi, blo, chi, clo;
    cvt8(av0, av1, ahi, alo);
    cvt8(bv0, bv1, bhi, blo);
    cvt8(cv0, cv1, chi, clo);

    __syncthreads();   // A: previous tile's readers done
    *(uint4*)&lds[        sa16 * 8]        = ahi;
    *(uint4*)&lds[4096  + sa16 * 8]        = alo;
    *(uint4*)&lds[8192  + sa16 * 8]        = bhi;
    *(uint4*)&lds[16384 + sa16 * 8]        = blo;
    *(uint4*)&lds[8192  + sa16 * 8 + 4096] = chi;   // B rows 128..255
    *(uint4*)&lds[16384 + sa16 * 8 + 4096] = clo;
    __syncthreads();   // B: staging visible

    bf16x8 ah[4], al_[4];
#pragma unroll
    for (int i = 0; i < 4; ++i) {
      ah[i]  = u2b(*(const uint4*)&lds[       (a16 + i * 64) * 8]);
      al_[i] = u2b(*(const uint4*)&lds[4096 + (a16 + i * 64) * 8]);
    }
#pragma unroll
    for (int j = 0; j < 4; ++j) {
      const bf16x8 bh = u2b(*(const uint4*)&lds[8192  + (b16 + j * 64) * 8]);
      const bf16x8 bl = u2b(*(const uint4*)&lds[16384 + (b16 + j * 64) * 8]);
#pragma unroll
      for (int i = 0; i < 4; ++i) {
        acc[i][j] = __builtin_amdgcn_mfma_f32_16x16x32_bf16(ah[i],  bh, acc[i][j], 0, 0, 0);
        acc[i][j] = __builtin_amdgcn_mfma_f32_16x16x32_bf16(al_[i], bh, acc[i][j], 0, 0, 0);
        acc[i][j] = __builtin_amdgcn_mfma_f32_16x16x32_bf16(ah[i],  bl, acc[i][j], 0, 0, 0);
      }
    }
  }

  // ---- epilogue: C frag elem (i,j,r): m = m0+wm*64+i*16+quad*4+r, n = n0b+wn*64+j*16+cq
  const int mb = m0 + wm * 64 + quad * 4;
  const int nb = n0b + wn * 64 + cq;

  if (MODE == 1) {
    const float g = gammap[0];
#pragma unroll
    for (int j = 0; j < 4; ++j) {
      const float bvj = bias[nb + j * 16];
#pragma unroll
      for (int i = 0; i < 4; ++i) {
#pragma unroll
        for (int r = 0; r < 4; ++r) {
          const size_t off = (size_t)(mb + i * 16 + r) * 512 + (nb + j * 16);
          out[off] = fmaf(g, acc[i][j][r] + bvj, xres[off]);
        }
      }
    }
  } else {  // MODE 4: VT[b][n][key] bf16
    const int b = m0 >> 12;
    const int key0 = (m0 & 4095) + wm * 64 + quad * 4;
#pragma unroll
    for (int j = 0; j < 4; ++j) {
      const float bvj = bias[nb + j * 16];
      const size_t rowo = (size_t)(b * 512 + nb + j * 16) * 4096;
#pragma unroll
      for (int i = 0; i < 4; ++i) {
        unsigned short o4[4];
#pragma unroll
        for (int r = 0; r < 4; ++r) o4[r] = f2bf(acc[i][j][r] + bvj);
        uint2 o;
        o.x = (unsigned int)o4[0] | ((unsigned int)o4[1] << 16);
        o.y = (unsigned int)o4[2] | ((unsigned int)o4[3] << 16);
        *(uint2*)&VT[rowo + key0 + i * 16] = o;
      }
    }
  }
}

// ================= MFMA flash attention (v6: full-width blocks) =================
// 256 blocks: b = bid&7 (XCD-affine), qt = bid>>3 (0..31). Block = 128 q-rows x 512 cols.
// 512 threads = 8 waves; wave w owns q-rows [w*16, w*16+16) across ALL 512 cols.
// vs v5: no ch-split -> S phase + softmax computed ONCE per row (was 2x), K LDS reads
// halve. acc doubles to 32 frags (128 VGPR); launch_bounds(512,2) caps VGPR at 256.
__global__ __launch_bounds__(512, 2)
void attn_mfma(const unsigned short* __restrict__ Qc,   // [32768][320] hi|lo
               const unsigned short* __restrict__ Kc,   // [32768][320] hi|lo
               const unsigned short* __restrict__ VT,   // [8][512][4096] bf16
               float* __restrict__ O)                   // [32768][512] fp32
{
  // klds 32x328 (10496) + vtl 512x32 (16384) + plds 8x(16x40) (5120) = 32000 ush = 64000 B
  __shared__ __align__(16) unsigned short smem[32000];
  unsigned short* klds = smem;              // 32 keys x 328 (320 data + 8 pad)
  unsigned short* vtl  = smem + 10496;      // 512 cols x 32 (key-slice, no pad)
  unsigned short* plds = smem + 26880;      // per-wave 16 rows x 40

  const int bid = blockIdx.x;
  const int b   = bid & 7;                  // XCD-affine batch
  const int qt  = bid >> 3;                 // 0..31
  const int r0  = (b << 12) + qt * 128;

  const int tid  = threadIdx.x;             // 0..511
  const int w    = tid >> 6;                // 0..7
  const int lane = tid & 63;
  const int quad = lane >> 4;
  const int cq   = lane & 15;

  // ---- persistent Q fragments (A-operand layout), rows r0 + w*16 + cq ----
  bf16x8 qhi[5], qlo[5];
  {
    const size_t qrow = (size_t)(r0 + w * 16 + cq) * 320;
#pragma unroll
    for (int c = 0; c < 5; ++c) {
      qhi[c] = u2b(*(const uint4*)(Qc + qrow + c * 32 + quad * 8));
      qlo[c] = u2b(*(const uint4*)(Qc + qrow + 160 + c * 32 + quad * 8));
    }
  }

  f32x4 acc4[32];
#pragma unroll
  for (int i = 0; i < 32; ++i) acc4[i] = (f32x4){0.f, 0.f, 0.f, 0.f};
  float mreg[4], lreg[4];
#pragma unroll
  for (int r = 0; r < 4; ++r) { mreg[r] = -3.0e38f; lreg[r] = 0.f; }

  const int vqd = (tid & 3) * 8;        // V key sub-offset (8 ushorts)
  const int vc  = tid >> 2;             // 0..127 column group

  // K staging geometry (1280 uint4 cells): p = tid, tid+512, (tid<256: tid+1024)
  const int krow0 = tid / 40,          kc0 = (tid - krow0 * 40) * 8;
  const int krow1 = (tid + 512) / 40,  kc1 = ((tid + 512) - krow1 * 40) * 8;
  const int krow2 = (tid + 1024) / 40, kc2 = ((tid + 1024) - krow2 * 40) * 8;

  uint4 pk0, pk1, pk2, pv0, pv1, pv2, pv3;
  // ---- initial prefetch (tile 0) ----
  const unsigned short* kbase = Kc + (size_t)(b * 4096) * 320;
  const unsigned short* vbase = VT + ((size_t)(b * 512 + vc)) * 4096 + vqd;
  {
    pk0 = *(const uint4*)(kbase + (size_t)tid * 8);
    pk1 = *(const uint4*)(kbase + (size_t)(tid + 512) * 8);
    if (tid < 256) pk2 = *(const uint4*)(kbase + (size_t)(tid + 1024) * 8);
    pv0 = *(const uint4*)(vbase);
    pv1 = *(const uint4*)(vbase + (size_t)128 * 4096);
    pv2 = *(const uint4*)(vbase + (size_t)256 * 4096);
    pv3 = *(const uint4*)(vbase + (size_t)384 * 4096);
  }

  for (int kt = 0; kt < 128; ++kt) {
    __syncthreads();  // A: previous tile's LDS readers done; drains prefetch loads

    // ---- stage prefetched K / V tiles into LDS ----
    *(uint4*)&klds[krow0 * 328 + kc0] = pk0;
    *(uint4*)&klds[krow1 * 328 + kc1] = pk1;
    if (tid < 256) *(uint4*)&klds[krow2 * 328 + kc2] = pk2;
    *(uint4*)&vtl[(vc      ) * 32 + vqd] = pv0;
    *(uint4*)&vtl[(vc + 128) * 32 + vqd] = pv1;
    *(uint4*)&vtl[(vc + 256) * 32 + vqd] = pv2;
    *(uint4*)&vtl[(vc + 384) * 32 + vqd] = pv3;

    __syncthreads();  // B: staging visible

    // ---- issue prefetch for next tile (in flight during S+softmax+PV) ----
    {
      const int ktn = (kt < 127) ? kt + 1 : 127;
      pk0 = *(const uint4*)(kbase + (size_t)(ktn * 32 * 320) + (size_t)tid * 8);
      pk1 = *(const uint4*)(kbase + (size_t)(ktn * 32 * 320) + (size_t)(tid + 512) * 8);
      if (tid < 256) pk2 = *(const uint4*)(kbase + (size_t)(ktn * 32 * 320) + (size_t)(tid + 1024) * 8);
      pv0 = *(const uint4*)(vbase + ktn * 32);
      pv1 = *(const uint4*)(vbase + (size_t)128 * 4096 + ktn * 32);
      pv2 = *(const uint4*)(vbase + (size_t)256 * 4096 + ktn * 32);
      pv3 = *(const uint4*)(vbase + (size_t)384 * 4096 + ktn * 32);
    }

    // ---- S phase: wave w -> rows [w*16, w*16+16) x 32 keys ----
    f32x4 S0 = (f32x4){0.f, 0.f, 0.f, 0.f};
    f32x4 S1 = (f32x4){0.f, 0.f, 0.f, 0.f};
#pragma unroll
    for (int c = 0; c < 5; ++c) {
      const int ko = c * 32 + quad * 8;
      const bf16x8 kh0 = u2b(*(const uint4*)&klds[cq * 328 + ko]);
      const bf16x8 kl0 = u2b(*(const uint4*)&klds[cq * 328 + 160 + ko]);
      const bf16x8 kh1 = u2b(*(const uint4*)&klds[(16 + cq) * 328 + ko]);
      const bf16x8 kl1 = u2b(*(const uint4*)&klds[(16 + cq) * 328 + 160 + ko]);
      S0 = __builtin_amdgcn_mfma_f32_16x16x32_bf16(qhi[c], kh0, S0, 0, 0, 0);
      S1 = __builtin_amdgcn_mfma_f32_16x16x32_bf16(qhi[c], kh1, S1, 0, 0, 0);
      S0 = __builtin_amdgcn_mfma_f32_16x16x32_bf16(qhi[c], kl0, S0, 0, 0, 0);
      S1 = __builtin_amdgcn_mfma_f32_16x16x32_bf16(qhi[c], kl1, S1, 0, 0, 0);
      S0 = __builtin_amdgcn_mfma_f32_16x16x32_bf16(qlo[c], kh0, S0, 0, 0, 0);
      S1 = __builtin_amdgcn_mfma_f32_16x16x32_bf16(qlo[c], kh1, S1, 0, 0, 0);
    }

    // ---- wave-local online softmax (row = quad*4+r, keys cq / 16+cq) ----
    unsigned short* pw = plds + w * 640;
    float alph[4];
    bool upd = false;
#pragma unroll
    for (int r = 0; r < 4; ++r) {
      const float s0 = S0[r], s1 = S1[r];
      float t = fmaxf(s0, s1);
      t = fmaxf(t, __shfl_xor(t, 1));
      t = fmaxf(t, __shfl_xor(t, 2));
      t = fmaxf(t, __shfl_xor(t, 4));
      t = fmaxf(t, __shfl_xor(t, 8));
      const float mo = mreg[r];
      const float mn = fmaxf(mo, t);
      upd = upd || (mn > mo);
      const float al = __expf(mo - mn);
      const float p0 = __expf(s0 - mn);
      const float p1 = __expf(s1 - mn);
      float ts = p0 + p1;
      ts += __shfl_xor(ts, 1);
      ts += __shfl_xor(ts, 2);
      ts += __shfl_xor(ts, 4);
      ts += __shfl_xor(ts, 8);
      lreg[r] = lreg[r] * al + ts;
      mreg[r] = mn;
      alph[r] = al;
      const int prow = (quad * 4 + r) * 40;
      pw[prow + cq]      = f2bf(p0);
      pw[prow + 16 + cq] = f2bf(p1);
    }

    if (__any(upd)) {
#pragma unroll
      for (int i = 0; i < 32; ++i) {
        acc4[i][0] *= alph[0]; acc4[i][1] *= alph[1];
        acc4[i][2] *= alph[2]; acc4[i][3] *= alph[3];
      }
    }

    // ---- PV phase (wave-local): rows [w*16..) x all 512 cols ----
    const bf16x8 pa = u2b(*(const uint4*)&pw[cq * 40 + quad * 8]);
#pragma unroll
    for (int i = 0; i < 32; ++i) {
      const bf16x8 vb = u2b(*(const uint4*)&vtl[(i * 16 + cq) * 32 + quad * 8]);
      acc4[i] = __builtin_amdgcn_mfma_f32_16x16x32_bf16(pa, vb, acc4[i], 0, 0, 0);
    }
  }

  // ---- epilogue: O = acc/l, staged through LDS (64-col eighths) ----
  float inv[4];
#pragma unroll
  for (int r = 0; r < 4; ++r) inv[r] = 1.f / lreg[r];

  __syncthreads();  // all waves done with klds/vtl before overlay
  float* ep = (float*)smem + w * 1088;     // 16 rows x 68 fp32 per wave (4352 B)
  const int r0w = r0 + w * 16;
#pragma unroll
  for (int qtr = 0; qtr < 8; ++qtr) {
#pragma unroll
    for (int ii = 0; ii < 4; ++ii)
#pragma unroll
      for (int r = 0; r < 4; ++r)
        ep[(quad * 4 + r) * 68 + ii * 16 + cq] = acc4[qtr * 4 + ii][r] * inv[r];
    // wave-private RAW; ds ops complete in order per wave
#pragma unroll
    for (int t = 0; t < 4; ++t) {
      const int flat4 = t * 64 + lane;     // 0..255 float4 units (16 rows x 16)
      const int row = flat4 >> 4;          // 0..15
      const int c4 = flat4 & 15;
      const float4 val = *(const float4*)&ep[row * 68 + c4 * 4];
      *(float4*)&O[(size_t)(r0w + row) * CDIM + qtr * 64 + c4 * 4] = val;
    }
  }
}

extern "C" void kernel_launch(void* const* d_in, const int* in_sizes, int n_in,
                              void* d_out, int out_size, void* d_ws, size_t ws_size,
                              hipStream_t stream)
{
  const float* x     = (const float*)d_in[0];
  const float* Wq    = (const float*)d_in[1];
  const float* bq    = (const float*)d_in[2];
  const float* Wk    = (const float*)d_in[3];
  const float* bk    = (const float*)d_in[4];
  const float* Wv    = (const float*)d_in[5];
  const float* bv    = (const float*)d_in[6];
  const float* Wres  = (const float*)d_in[7];
  const float* bres  = (const float*)d_in[8];
  const float* gamma = (const float*)d_in[9];

  float* seg_map  = (float*)d_out;                         // 32768 x 150
  float* feat_map = seg_map + (size_t)M_ROWS * KRANK;      // 32768 x 512

  unsigned short* Qcomb = (unsigned short*)d_ws;                       // [32768][320]
  unsigned short* Kcomb = Qcomb + (size_t)M_ROWS * 320;                // [32768][320]
  unsigned short* VTb   = Kcomb + (size_t)M_ROWS * 320;                // [8][512][4096]
  float*          feats = (float*)(VTb + (size_t)M_ROWS * CDIM);       // [32768][512]

  dim3 blk(256);
  gemm_nt<2><<<dim3(2, 256), blk, 0, stream>>>(x, Wq, bq, seg_map, KRANK, KRANK, nullptr, nullptr, Qcomb);
  gemm_nt<3><<<dim3(2, 256), blk, 0, stream>>>(x, Wk, bk, nullptr,  KRANK, KRANK, nullptr, nullptr, Kcomb);
  mgemm_nt<4><<<dim3(2, 256), dim3(512), 0, stream>>>(x, Wv, bv, nullptr, nullptr, nullptr, VTb);
  attn_mfma<<<dim3(256), dim3(512), 0, stream>>>(Qcomb, Kcomb, VTb, feats);
  mgemm_nt<1><<<dim3(2, 256), dim3(512), 0, stream>>>(feats, Wres, bres, feat_map, x, gamma, nullptr);
}

// Round 3
// 811.178 us; speedup vs baseline: 1.7603x; 1.0898x over previous
//
#include <hip/hip_runtime.h>
#include <cstdint>
#include <cstddef>

#define M_ROWS 32768   // B*N
#define CDIM   512
#define KRANK  150
#define KPAD   160     // padded rank for MFMA (zeros beyond 150)

typedef __bf16 bf16x8 __attribute__((ext_vector_type(8)));
typedef float  f32x4  __attribute__((ext_vector_type(4)));

union U16B { uint4 u; bf16x8 b; };
static __device__ __forceinline__ bf16x8 u2b(uint4 u) { U16B x; x.u = u; return x.b; }

static __device__ __forceinline__ unsigned short f2bf(float f) {
  uint32_t u = __float_as_uint(f);
  u += 0x7fffu + ((u >> 16) & 1u);
  return (unsigned short)(u >> 16);
}

// split 8 fp32 into hi/lo bf16 (hi = RNE(v), lo = RNE(v - hi)); err ~2^-16 rel
static __device__ __forceinline__ void cvt8(float4 a, float4 b, uint4& h, uint4& l) {
  float v[8] = {a.x, a.y, a.z, a.w, b.x, b.y, b.z, b.w};
  unsigned short hs[8], ls[8];
#pragma unroll
  for (int i = 0; i < 8; ++i) {
    hs[i] = f2bf(v[i]);
    const float hf = __uint_as_float((uint32_t)hs[i] << 16);
    ls[i] = f2bf(v[i] - hf);
  }
  h = *(uint4*)&hs[0];
  l = *(uint4*)&ls[0];
}

// ================= MFMA hi/lo GEMM (fp32-accurate via 3-product bf16) =================
// out[m][n] = sum_k A[m][k]*W[n][k] (+bias).  M=32768, K=512.
// Tile: 128m x 256n per block, 8 waves (2m x 4n), wave tile 64x64 = 4x4 16x16 frags.
// K-step 32. LDS pair-swizzled at 16B-cell granularity:
//   addr16(row,k4) = (row>>1)*8 + (((row&1)*4 + k4) ^ ((row>>1)&7))
// MODE 4: VT output bf16 [b][col][4096] (+bias).  MODE 1: out = gamma*(acc+bias)+xres.
// MODE 2: Q proj: fp32 out [m][150] + aux packed hi/lo [m][320] (cols>=150 zero); grid x=1.
// MODE 3: K proj: aux only; grid x=1. (W has 150 rows; rows >=150 staged as zero.)
template<int MODE>
__global__ __launch_bounds__(512, 4)
void mgemm_nt(const float* __restrict__ A, const float* __restrict__ W,
              const float* __restrict__ bias, float* __restrict__ out,
              const float* __restrict__ xres, const float* __restrict__ gammap,
              unsigned short* __restrict__ aux)
{
  // regions (ushort offsets): AH 0 (4096), AL 4096, BH 8192 (8192), BL 16384. 49152 B.
  __shared__ __align__(16) unsigned short lds[24576];
  const int tid = threadIdx.x;
  const int m0  = blockIdx.y * 128;
  const int n0b = blockIdx.x * 256;

  // ---- staging geometry: A = 512 cells (1/thread), B = 1024 cells (2/thread) ----
  const int srow = tid >> 2, sk4 = tid & 3;
  const int sa16 = ((srow >> 1) << 3) + ((((srow & 1) << 2) | sk4) ^ ((srow >> 1) & 7));
  const float* ap  = A + (size_t)(m0 + srow) * 512 + sk4 * 8;
  const float* bp0 = W + (size_t)(n0b + srow) * 512 + sk4 * 8;
  const float* bp1 = W + (size_t)(n0b + 128 + srow) * 512 + sk4 * 8;
  // MODE 2/3: W has only 150 rows; bp0 rows 0..127 always valid, bp1 valid iff srow<22
  const bool b1ok = (MODE == 1 || MODE == 4) || (srow < (KRANK - 128));

  // ---- fragment geometry ----
  const int lane = tid & 63, w = tid >> 6;
  const int wm = w >> 2, wn = w & 3;
  const int cq = lane & 15, quad = lane >> 4;
  const int fsub = (((cq & 1) << 2) | quad) ^ (cq >> 1);
  const int a16 = wm * 256 + ((cq >> 1) << 3) + fsub;   // + i*64 cells
  const int b16 = wn * 256 + ((cq >> 1) << 3) + fsub;   // + j*64 cells

  f32x4 acc[4][4];
#pragma unroll
  for (int i = 0; i < 4; ++i)
#pragma unroll
    for (int j = 0; j < 4; ++j) acc[i][j] = (f32x4){0.f, 0.f, 0.f, 0.f};

  for (int kt = 0; kt < 512; kt += 32) {
    const float4 av0 = *(const float4*)(ap + kt);
    const float4 av1 = *(const float4*)(ap + kt + 4);
    const float4 bv0 = *(const float4*)(bp0 + kt);
    const float4 bv1 = *(const float4*)(bp0 + kt + 4);
    float4 cv0 = make_float4(0.f, 0.f, 0.f, 0.f), cv1 = cv0;
    if (b1ok) { cv0 = *(const float4*)(bp1 + kt); cv1 = *(const float4*)(bp1 + kt + 4); }
    uint4 ahi, alo, bhi, blo, chi, clo;
    cvt8(av0, av1, ahi, alo);
    cvt8(bv0, bv1, bhi, blo);
    cvt8(cv0, cv1, chi, clo);

    __syncthreads();   // A: previous tile's readers done
    *(uint4*)&lds[        sa16 * 8]        = ahi;
    *(uint4*)&lds[4096  + sa16 * 8]        = alo;
    *(uint4*)&lds[8192  + sa16 * 8]        = bhi;
    *(uint4*)&lds[16384 + sa16 * 8]        = blo;
    *(uint4*)&lds[8192  + sa16 * 8 + 4096] = chi;   // B rows 128..255
    *(uint4*)&lds[16384 + sa16 * 8 + 4096] = clo;
    __syncthreads();   // B: staging visible

    bf16x8 ah[4], al_[4];
#pragma unroll
    for (int i = 0; i < 4; ++i) {
      ah[i]  = u2b(*(const uint4*)&lds[       (a16 + i * 64) * 8]);
      al_[i] = u2b(*(const uint4*)&lds[4096 + (a16 + i * 64) * 8]);
    }
#pragma unroll
    for (int j = 0; j < 4; ++j) {
      const bf16x8 bh = u2b(*(const uint4*)&lds[8192  + (b16 + j * 64) * 8]);
      const bf16x8 bl = u2b(*(const uint4*)&lds[16384 + (b16 + j * 64) * 8]);
#pragma unroll
      for (int i = 0; i < 4; ++i) {
        acc[i][j] = __builtin_amdgcn_mfma_f32_16x16x32_bf16(ah[i],  bh, acc[i][j], 0, 0, 0);
        acc[i][j] = __builtin_amdgcn_mfma_f32_16x16x32_bf16(al_[i], bh, acc[i][j], 0, 0, 0);
        acc[i][j] = __builtin_amdgcn_mfma_f32_16x16x32_bf16(ah[i],  bl, acc[i][j], 0, 0, 0);
      }
    }
  }

  // ---- epilogue: C frag elem (i,j,r): m = m0+wm*64+i*16+quad*4+r, n = n0b+wn*64+j*16+cq
  const int mb = m0 + wm * 64 + quad * 4;
  const int nb = n0b + wn * 64 + cq;

  if (MODE == 1) {
    const float g = gammap[0];
#pragma unroll
    for (int j = 0; j < 4; ++j) {
      const float bvj = bias[nb + j * 16];
#pragma unroll
      for (int i = 0; i < 4; ++i) {
#pragma unroll
        for (int r = 0; r < 4; ++r) {
          const size_t off = (size_t)(mb + i * 16 + r) * 512 + (nb + j * 16);
          out[off] = fmaf(g, acc[i][j][r] + bvj, xres[off]);
        }
      }
    }
  } else if (MODE == 4) {  // VT[b][n][key] bf16
    const int b = m0 >> 12;
    const int key0 = (m0 & 4095) + wm * 64 + quad * 4;
#pragma unroll
    for (int j = 0; j < 4; ++j) {
      const float bvj = bias[nb + j * 16];
      const size_t rowo = (size_t)(b * 512 + nb + j * 16) * 4096;
#pragma unroll
      for (int i = 0; i < 4; ++i) {
        unsigned short o4[4];
#pragma unroll
        for (int r = 0; r < 4; ++r) o4[r] = f2bf(acc[i][j][r] + bvj);
        uint2 o;
        o.x = (unsigned int)o4[0] | ((unsigned int)o4[1] << 16);
        o.y = (unsigned int)o4[2] | ((unsigned int)o4[3] << 16);
        *(uint2*)&aux[rowo + key0 + i * 16] = o;
      }
    }
  } else {  // MODE 2 / 3: Q/K projection outputs
#pragma unroll
    for (int j = 0; j < 4; ++j) {
      const int n = nb + j * 16;
      if (n < KPAD) {
        const float bvj = (n < KRANK) ? bias[n] : 0.f;
#pragma unroll
        for (int i = 0; i < 4; ++i) {
#pragma unroll
          for (int r = 0; r < 4; ++r) {
            const int m = mb + i * 16 + r;
            float v = (n < KRANK) ? (acc[i][j][r] + bvj) : 0.f;
            if (MODE == 2 && n < KRANK) out[(size_t)m * KRANK + n] = v;
            const unsigned short h = f2bf(v);
            aux[(size_t)m * 320 + n] = h;
            const float hf = __uint_as_float(((uint32_t)h) << 16);
            aux[(size_t)m * 320 + 160 + n] = f2bf(v - hf);
          }
        }
      }
    }
  }
}

// ================= MFMA flash attention (v7: conflict-free V planes) =================
// 256 blocks: b = bid&7 (XCD-affine), qt = bid>>3 (0..31). Block = 128 q-rows x 512 cols.
// 512 threads = 8 waves; wave w owns q-rows [w*16, w*16+16) across ALL 512 cols.
// vtl layout: 4 key-slice planes [c][col][8], plane stride 4112 ush (bank-shift 8):
// both the staging write (lane -> banks 8c+4vc) and the PV read (lane -> banks
// 8*quad+4*cq) cover 8 distinct 4-bank spans per 8-lane phase -> conflict-free.
__global__ __launch_bounds__(512, 2)
void attn_mfma(const unsigned short* __restrict__ Qc,   // [32768][320] hi|lo
               const unsigned short* __restrict__ Kc,   // [32768][320] hi|lo
               const unsigned short* __restrict__ VT,   // [8][512][4096] bf16
               float* __restrict__ O)                   // [32768][512] fp32
{
  // klds 32x328 (10496) + vtl 4x4112 (16448) + plds 8x(16x40) (5120) = 32064 ush = 64128 B
  __shared__ __align__(16) unsigned short smem[32064];
  unsigned short* klds = smem;              // 32 keys x 328 (320 data + 8 pad)
  unsigned short* vtl  = smem + 10496;      // 4 planes x [512 cols][8 keys]
  unsigned short* plds = smem + 26944;      // per-wave 16 rows x 40

  const int bid = blockIdx.x;
  const int b   = bid & 7;                  // XCD-affine batch
  const int qt  = bid >> 3;                 // 0..31
  const int r0  = (b << 12) + qt * 128;

  const int tid  = threadIdx.x;             // 0..511
  const int w    = tid >> 6;                // 0..7
  const int lane = tid & 63;
  const int quad = lane >> 4;
  const int cq   = lane & 15;

  // ---- persistent Q fragments (A-operand layout), rows r0 + w*16 + cq ----
  bf16x8 qhi[5], qlo[5];
  {
    const size_t qrow = (size_t)(r0 + w * 16 + cq) * 320;
#pragma unroll
    for (int c = 0; c < 5; ++c) {
      qhi[c] = u2b(*(const uint4*)(Qc + qrow + c * 32 + quad * 8));
      qlo[c] = u2b(*(const uint4*)(Qc + qrow + 160 + c * 32 + quad * 8));
    }
  }

  f32x4 acc4[32];
#pragma unroll
  for (int i = 0; i < 32; ++i) acc4[i] = (f32x4){0.f, 0.f, 0.f, 0.f};
  float mreg[4], lreg[4];
#pragma unroll
  for (int r = 0; r < 4; ++r) { mreg[r] = -3.0e38f; lreg[r] = 0.f; }

  const int vqd = (tid & 3) * 8;        // V key sub-offset (8 ushorts) = plane index *8
  const int vc  = tid >> 2;             // 0..127 column group
  const int vwb = (tid & 3) * 4112 + vc * 8;    // LDS write base (plane, col)
  const int vrb = quad * 4112 + cq * 8;          // LDS read base (+ i*128)

  // K staging geometry (1280 uint4 cells): p = tid, tid+512, (tid<256: tid+1024)
  const int krow0 = tid / 40,          kc0 = (tid - krow0 * 40) * 8;
  const int krow1 = (tid + 512) / 40,  kc1 = ((tid + 512) - krow1 * 40) * 8;
  const int krow2 = (tid + 1024) / 40, kc2 = ((tid + 1024) - krow2 * 40) * 8;

  uint4 pk0, pk1, pk2, pv0, pv1, pv2, pv3;
  // ---- initial prefetch (tile 0) ----
  const unsigned short* kbase = Kc + (size_t)(b * 4096) * 320;
  const unsigned short* vbase = VT + ((size_t)(b * 512 + vc)) * 4096 + vqd;
  {
    pk0 = *(const uint4*)(kbase + (size_t)tid * 8);
    pk1 = *(const uint4*)(kbase + (size_t)(tid + 512) * 8);
    if (tid < 256) pk2 = *(const uint4*)(kbase + (size_t)(tid + 1024) * 8);
    pv0 = *(const uint4*)(vbase);
    pv1 = *(const uint4*)(vbase + (size_t)128 * 4096);
    pv2 = *(const uint4*)(vbase + (size_t)256 * 4096);
    pv3 = *(const uint4*)(vbase + (size_t)384 * 4096);
  }

  for (int kt = 0; kt < 128; ++kt) {
    __syncthreads();  // A: previous tile's LDS readers done; drains prefetch loads

    // ---- stage prefetched K / V tiles into LDS ----
    *(uint4*)&klds[krow0 * 328 + kc0] = pk0;
    *(uint4*)&klds[krow1 * 328 + kc1] = pk1;
    if (tid < 256) *(uint4*)&klds[krow2 * 328 + kc2] = pk2;
    *(uint4*)&vtl[vwb]        = pv0;
    *(uint4*)&vtl[vwb + 1024] = pv1;
    *(uint4*)&vtl[vwb + 2048] = pv2;
    *(uint4*)&vtl[vwb + 3072] = pv3;

    __syncthreads();  // B: staging visible

    // ---- issue prefetch for next tile (in flight during S+softmax+PV) ----
    {
      const int ktn = (kt < 127) ? kt + 1 : 127;
      pk0 = *(const uint4*)(kbase + (size_t)(ktn * 32 * 320) + (size_t)tid * 8);
      pk1 = *(const uint4*)(kbase + (size_t)(ktn * 32 * 320) + (size_t)(tid + 512) * 8);
      if (tid < 256) pk2 = *(const uint4*)(kbase + (size_t)(ktn * 32 * 320) + (size_t)(tid + 1024) * 8);
      pv0 = *(const uint4*)(vbase + ktn * 32);
      pv1 = *(const uint4*)(vbase + (size_t)128 * 4096 + ktn * 32);
      pv2 = *(const uint4*)(vbase + (size_t)256 * 4096 + ktn * 32);
      pv3 = *(const uint4*)(vbase + (size_t)384 * 4096 + ktn * 32);
    }

    // ---- S phase: wave w -> rows [w*16, w*16+16) x 32 keys ----
    f32x4 S0 = (f32x4){0.f, 0.f, 0.f, 0.f};
    f32x4 S1 = (f32x4){0.f, 0.f, 0.f, 0.f};
#pragma unroll
    for (int c = 0; c < 5; ++c) {
      const int ko = c * 32 + quad * 8;
      const bf16x8 kh0 = u2b(*(const uint4*)&klds[cq * 328 + ko]);
      const bf16x8 kl0 = u2b(*(const uint4*)&klds[cq * 328 + 160 + ko]);
      const bf16x8 kh1 = u2b(*(const uint4*)&klds[(16 + cq) * 328 + ko]);
      const bf16x8 kl1 = u2b(*(const uint4*)&klds[(16 + cq) * 328 + 160 + ko]);
      S0 = __builtin_amdgcn_mfma_f32_16x16x32_bf16(qhi[c], kh0, S0, 0, 0, 0);
      S1 = __builtin_amdgcn_mfma_f32_16x16x32_bf16(qhi[c], kh1, S1, 0, 0, 0);
      S0 = __builtin_amdgcn_mfma_f32_16x16x32_bf16(qhi[c], kl0, S0, 0, 0, 0);
      S1 = __builtin_amdgcn_mfma_f32_16x16x32_bf16(qhi[c], kl1, S1, 0, 0, 0);
      S0 = __builtin_amdgcn_mfma_f32_16x16x32_bf16(qlo[c], kh0, S0, 0, 0, 0);
      S1 = __builtin_amdgcn_mfma_f32_16x16x32_bf16(qlo[c], kh1, S1, 0, 0, 0);
    }

    // ---- wave-local online softmax (row = quad*4+r, keys cq / 16+cq) ----
    unsigned short* pw = plds + w * 640;
    float alph[4];
    bool upd = false;
#pragma unroll
    for (int r = 0; r < 4; ++r) {
      const float s0 = S0[r], s1 = S1[r];
      float t = fmaxf(s0, s1);
      t = fmaxf(t, __shfl_xor(t, 1));
      t = fmaxf(t, __shfl_xor(t, 2));
      t = fmaxf(t, __shfl_xor(t, 4));
      t = fmaxf(t, __shfl_xor(t, 8));
      const float mo = mreg[r];
      const float mn = fmaxf(mo, t);
      upd = upd || (mn > mo);
      const float al = __expf(mo - mn);
      const float p0 = __expf(s0 - mn);
      const float p1 = __expf(s1 - mn);
      float ts = p0 + p1;
      ts += __shfl_xor(ts, 1);
      ts += __shfl_xor(ts, 2);
      ts += __shfl_xor(ts, 4);
      ts += __shfl_xor(ts, 8);
      lreg[r] = lreg[r] * al + ts;
      mreg[r] = mn;
      alph[r] = al;
      const int prow = (quad * 4 + r) * 40;
      pw[prow + cq]      = f2bf(p0);
      pw[prow + 16 + cq] = f2bf(p1);
    }

    if (__any(upd)) {
#pragma unroll
      for (int i = 0; i < 32; ++i) {
        acc4[i][0] *= alph[0]; acc4[i][1] *= alph[1];
        acc4[i][2] *= alph[2]; acc4[i][3] *= alph[3];
      }
    }

    // ---- PV phase (wave-local): rows [w*16..) x all 512 cols ----
    const bf16x8 pa = u2b(*(const uint4*)&pw[cq * 40 + quad * 8]);
#pragma unroll
    for (int i = 0; i < 32; ++i) {
      const bf16x8 vb = u2b(*(const uint4*)&vtl[vrb + i * 128]);
      acc4[i] = __builtin_amdgcn_mfma_f32_16x16x32_bf16(pa, vb, acc4[i], 0, 0, 0);
    }
  }

  // ---- epilogue: O = acc/l, staged through LDS (64-col eighths) ----
  float inv[4];
#pragma unroll
  for (int r = 0; r < 4; ++r) inv[r] = 1.f / lreg[r];

  __syncthreads();  // all waves done with klds/vtl before overlay
  float* ep = (float*)smem + w * 1088;     // 16 rows x 68 fp32 per wave (4352 B)
  const int r0w = r0 + w * 16;
#pragma unroll
  for (int qtr = 0; qtr < 8; ++qtr) {
#pragma unroll
    for (int ii = 0; ii < 4; ++ii)
#pragma unroll
      for (int r = 0; r < 4; ++r)
        ep[(quad * 4 + r) * 68 + ii * 16 + cq] = acc4[qtr * 4 + ii][r] * inv[r];
    // wave-private RAW; ds ops complete in order per wave
#pragma unroll
    for (int t = 0; t < 4; ++t) {
      const int flat4 = t * 64 + lane;     // 0..255 float4 units (16 rows x 16)
      const int row = flat4 >> 4;          // 0..15
      const int c4 = flat4 & 15;
      const float4 val = *(const float4*)&ep[row * 68 + c4 * 4];
      *(float4*)&O[(size_t)(r0w + row) * CDIM + qtr * 64 + c4 * 4] = val;
    }
  }
}

extern "C" void kernel_launch(void* const* d_in, const int* in_sizes, int n_in,
                              void* d_out, int out_size, void* d_ws, size_t ws_size,
                              hipStream_t stream)
{
  const float* x     = (const float*)d_in[0];
  const float* Wq    = (const float*)d_in[1];
  const float* bq    = (const float*)d_in[2];
  const float* Wk    = (const float*)d_in[3];
  const float* bk    = (const float*)d_in[4];
  const float* Wv    = (const float*)d_in[5];
  const float* bv    = (const float*)d_in[6];
  const float* Wres  = (const float*)d_in[7];
  const float* bres  = (const float*)d_in[8];
  const float* gamma = (const float*)d_in[9];

  float* seg_map  = (float*)d_out;                         // 32768 x 150
  float* feat_map = seg_map + (size_t)M_ROWS * KRANK;      // 32768 x 512

  unsigned short* Qcomb = (unsigned short*)d_ws;                       // [32768][320]
  unsigned short* Kcomb = Qcomb + (size_t)M_ROWS * 320;                // [32768][320]
  unsigned short* VTb   = Kcomb + (size_t)M_ROWS * 320;                // [8][512][4096]
  float*          feats = (float*)(VTb + (size_t)M_ROWS * CDIM);       // [32768][512]

  mgemm_nt<2><<<dim3(1, 256), dim3(512), 0, stream>>>(x, Wq, bq, seg_map, nullptr, nullptr, Qcomb);
  mgemm_nt<3><<<dim3(1, 256), dim3(512), 0, stream>>>(x, Wk, bk, nullptr, nullptr, nullptr, Kcomb);
  mgemm_nt<4><<<dim3(2, 256), dim3(512), 0, stream>>>(x, Wv, bv, nullptr, nullptr, nullptr, VTb);
  attn_mfma<<<dim3(256), dim3(512), 0, stream>>>(Qcomb, Kcomb, VTb, feats);
  mgemm_nt<1><<<dim3(2, 256), dim3(512), 0, stream>>>(feats, Wres, bres, feat_map, x, gamma, nullptr);
}

// Round 4
// 771.631 us; speedup vs baseline: 1.8505x; 1.0513x over previous
//
#include <hip/hip_runtime.h>
#include <cstdint>
#include <cstddef>

#define M_ROWS 32768   // B*N
#define CDIM   512
#define KRANK  150
#define KPAD   160     // padded rank for MFMA (zeros beyond 150)

typedef __bf16 bf16x8 __attribute__((ext_vector_type(8)));
typedef float  f32x4  __attribute__((ext_vector_type(4)));

union U16B { uint4 u; bf16x8 b; };
static __device__ __forceinline__ bf16x8 u2b(uint4 u) { U16B x; x.u = u; return x.b; }

static __device__ __forceinline__ unsigned short f2bf(float f) {
  uint32_t u = __float_as_uint(f);
  u += 0x7fffu + ((u >> 16) & 1u);
  return (unsigned short)(u >> 16);
}

// split 8 fp32 into hi/lo bf16 (hi = RNE(v), lo = RNE(v - hi)); err ~2^-16 rel
static __device__ __forceinline__ void cvt8(float4 a, float4 b, uint4& h, uint4& l) {
  float v[8] = {a.x, a.y, a.z, a.w, b.x, b.y, b.z, b.w};
  unsigned short hs[8], ls[8];
#pragma unroll
  for (int i = 0; i < 8; ++i) {
    hs[i] = f2bf(v[i]);
    const float hf = __uint_as_float((uint32_t)hs[i] << 16);
    ls[i] = f2bf(v[i] - hf);
  }
  h = *(uint4*)&hs[0];
  l = *(uint4*)&ls[0];
}

// async global->LDS, 16B per lane (dest = wave-uniform base + lane*16)
static __device__ __forceinline__ void glds16(const void* g, void* l) {
  __builtin_amdgcn_global_load_lds(
      (const __attribute__((address_space(1))) unsigned int*)g,
      (__attribute__((address_space(3))) unsigned int*)l, 16, 0, 0);
}

// swizzled 16B-cell index used by mgemm LDS tiles (row 0..127, k4 0..3)
static __device__ __forceinline__ int sa16f(int row, int k4) {
  return ((row >> 1) << 3) + ((((row & 1) << 2) | k4) ^ ((row >> 1) & 7));
}

// ============== W -> pre-swizzled hi/lo bf16 B-images ==============
// Image per (ntile, kt): 2048 cells x 16B = 32KB, laid out EXACTLY as mgemm's
// B LDS region: cells [0,1024) = BH (rows 0-127 at sa16, rows 128-255 at 512+sa16),
// cells [1024,2048) = BL. Rows >= N are zero (kills in-kernel masking).
// jobs: [Wv:32][Wres:32][Wq:16][Wk:16] = 96 blocks x 512 threads.
__global__ __launch_bounds__(512)
void cvt_w(const float* __restrict__ Wv, const float* __restrict__ Wres,
           const float* __restrict__ Wq, const float* __restrict__ Wk,
           unsigned short* __restrict__ WvC, unsigned short* __restrict__ WresC,
           unsigned short* __restrict__ WqC, unsigned short* __restrict__ WkC)
{
  int job = blockIdx.x;
  const float* W; unsigned short* img; int N;
  if (job < 32)      { W = Wv;   img = WvC;   N = 512; }
  else if (job < 64) { W = Wres; img = WresC; N = 512; job -= 32; }
  else if (job < 80) { W = Wq;   img = WqC;   N = KRANK; job -= 64; }
  else               { W = Wk;   img = WkC;   N = KRANK; job -= 80; }
  const int nt = (N == 512) ? (job >> 4) : 0;
  const int kt = job & 15;

  const int tid = threadIdx.x;
  const int srow = tid >> 2, sk4 = tid & 3;
  const int sa = sa16f(srow, sk4);
  unsigned short* ib = img + (size_t)(nt * 16 + kt) * 16384;  // 2048 cells * 8 ush
#pragma unroll
  for (int h = 0; h < 2; ++h) {
    const int row = nt * 256 + h * 128 + srow;
    float4 v0 = make_float4(0.f, 0.f, 0.f, 0.f), v1 = v0;
    if (row < N) {
      v0 = *(const float4*)&W[(size_t)row * 512 + kt * 32 + sk4 * 8];
      v1 = *(const float4*)&W[(size_t)row * 512 + kt * 32 + sk4 * 8 + 4];
    }
    uint4 h4, l4; cvt8(v0, v1, h4, l4);
    const int cell = h * 512 + sa;
    *(uint4*)&ib[(size_t)cell * 8]          = h4;
    *(uint4*)&ib[(size_t)(1024 + cell) * 8] = l4;
  }
}

// ================= MFMA hi/lo GEMM (fp32-accurate via 3-product bf16) =================
// out[m][n] = sum_k A[m][k]*W[n][k] (+bias).  M=32768, K=512.
// Tile: 128m x 256n per block, 8 waves (2m x 4n), wave tile 64x64 = 4x4 16x16 frags.
// A reg-staged + cvt8 (pair-swizzled cells); B staged via global_load_lds from the
// pre-swizzled Wimg (4 wave-instructions / K-step, async across barrier A->B).
// MODE 4: VT output bf16 [b][col][4096] (+bias).  MODE 1: out = gamma*(acc+bias)+xres.
// MODE 2: Q proj: fp32 out [m][150] + aux packed hi/lo [m][320]; grid x=1.
// MODE 3: K proj: aux only; grid x=1.
template<int MODE>
__global__ __launch_bounds__(512, 4)
void mgemm_nt(const float* __restrict__ A, const unsigned short* __restrict__ Wimg,
              const float* __restrict__ bias, float* __restrict__ out,
              const float* __restrict__ xres, const float* __restrict__ gammap,
              unsigned short* __restrict__ aux)
{
  // regions (ushort offsets): AH 0 (4096), AL 4096, BH 8192 (8192), BL 16384. 49152 B.
  __shared__ __align__(16) unsigned short lds[24576];
  const int tid = threadIdx.x;
  const int m0  = blockIdx.y * 128;

  // ---- A staging geometry: 512 cells (1/thread) ----
  const int srow = tid >> 2, sk4 = tid & 3;
  const int sa16 = sa16f(srow, sk4);
  const float* ap = A + (size_t)(m0 + srow) * 512 + sk4 * 8;

  // ---- fragment geometry ----
  const int lane = tid & 63, w = tid >> 6;
  const int wm = w >> 2, wn = w & 3;
  const int cq = lane & 15, quad = lane >> 4;
  const int fsub = (((cq & 1) << 2) | quad) ^ (cq >> 1);
  const int a16 = wm * 256 + ((cq >> 1) << 3) + fsub;   // + i*64 cells
  const int b16 = wn * 256 + ((cq >> 1) << 3) + fsub;   // + j*64 cells

  // B image base for this n-tile; per-lane src offset within each image
  const unsigned short* ibase = Wimg + (size_t)(blockIdx.x * 16) * 16384
                              + (size_t)(w * 64 + lane) * 8;

  f32x4 acc[4][4];
#pragma unroll
  for (int i = 0; i < 4; ++i)
#pragma unroll
    for (int j = 0; j < 4; ++j) acc[i][j] = (f32x4){0.f, 0.f, 0.f, 0.f};

  for (int kt = 0; kt < 512; kt += 32) {
    const float4 av0 = *(const float4*)(ap + kt);
    const float4 av1 = *(const float4*)(ap + kt + 4);
    uint4 ahi, alo;
    cvt8(av0, av1, ahi, alo);

    __syncthreads();   // A: previous tile's readers done
    *(uint4*)&lds[       sa16 * 8] = ahi;
    *(uint4*)&lds[4096 + sa16 * 8] = alo;
    const unsigned short* src = ibase + (size_t)(kt >> 5) * 16384;
#pragma unroll
    for (int c = 0; c < 4; ++c)
      glds16(src + (size_t)c * 4096, &lds[8192 + (c * 512 + w * 64) * 8]);
    __syncthreads();   // B: ds + vmem->lds drained, staging visible

    bf16x8 ah[4], al_[4];
#pragma unroll
    for (int i = 0; i < 4; ++i) {
      ah[i]  = u2b(*(const uint4*)&lds[       (a16 + i * 64) * 8]);
      al_[i] = u2b(*(const uint4*)&lds[4096 + (a16 + i * 64) * 8]);
    }
#pragma unroll
    for (int j = 0; j < 4; ++j) {
      const bf16x8 bh = u2b(*(const uint4*)&lds[8192  + (b16 + j * 64) * 8]);
      const bf16x8 bl = u2b(*(const uint4*)&lds[16384 + (b16 + j * 64) * 8]);
#pragma unroll
      for (int i = 0; i < 4; ++i) {
        acc[i][j] = __builtin_amdgcn_mfma_f32_16x16x32_bf16(ah[i],  bh, acc[i][j], 0, 0, 0);
        acc[i][j] = __builtin_amdgcn_mfma_f32_16x16x32_bf16(al_[i], bh, acc[i][j], 0, 0, 0);
        acc[i][j] = __builtin_amdgcn_mfma_f32_16x16x32_bf16(ah[i],  bl, acc[i][j], 0, 0, 0);
      }
    }
  }

  // ---- epilogue: C frag elem (i,j,r): m = m0+wm*64+i*16+quad*4+r, n = n0b+wn*64+j*16+cq
  const int n0b = blockIdx.x * 256;
  const int mb = m0 + wm * 64 + quad * 4;
  const int nb = n0b + wn * 64 + cq;

  if (MODE == 1) {
    const float g = gammap[0];
#pragma unroll
    for (int j = 0; j < 4; ++j) {
      const float bvj = bias[nb + j * 16];
#pragma unroll
      for (int i = 0; i < 4; ++i) {
#pragma unroll
        for (int r = 0; r < 4; ++r) {
          const size_t off = (size_t)(mb + i * 16 + r) * 512 + (nb + j * 16);
          out[off] = fmaf(g, acc[i][j][r] + bvj, xres[off]);
        }
      }
    }
  } else if (MODE == 4) {  // VT[b][n][key] bf16
    const int b = m0 >> 12;
    const int key0 = (m0 & 4095) + wm * 64 + quad * 4;
#pragma unroll
    for (int j = 0; j < 4; ++j) {
      const float bvj = bias[nb + j * 16];
      const size_t rowo = (size_t)(b * 512 + nb + j * 16) * 4096;
#pragma unroll
      for (int i = 0; i < 4; ++i) {
        unsigned short o4[4];
#pragma unroll
        for (int r = 0; r < 4; ++r) o4[r] = f2bf(acc[i][j][r] + bvj);
        uint2 o;
        o.x = (unsigned int)o4[0] | ((unsigned int)o4[1] << 16);
        o.y = (unsigned int)o4[2] | ((unsigned int)o4[3] << 16);
        *(uint2*)&aux[rowo + key0 + i * 16] = o;
      }
    }
  } else {  // MODE 2 / 3: Q/K projection outputs
#pragma unroll
    for (int j = 0; j < 4; ++j) {
      const int n = nb + j * 16;
      if (n < KPAD) {
        const float bvj = (n < KRANK) ? bias[n] : 0.f;
#pragma unroll
        for (int i = 0; i < 4; ++i) {
#pragma unroll
          for (int r = 0; r < 4; ++r) {
            const int m = mb + i * 16 + r;
            float v = (n < KRANK) ? (acc[i][j][r] + bvj) : 0.f;
            if (MODE == 2 && n < KRANK) out[(size_t)m * KRANK + n] = v;
            const unsigned short h = f2bf(v);
            aux[(size_t)m * 320 + n] = h;
            const float hf = __uint_as_float(((uint32_t)h) << 16);
            aux[(size_t)m * 320 + 160 + n] = f2bf(v - hf);
          }
        }
      }
    }
  }
}

// ================= MFMA flash attention (v8: defer-max + setprio) =================
// 256 blocks: b = bid&7 (XCD-affine), qt = bid>>3 (0..31). Block = 128 q-rows x 512 cols.
// 512 threads = 8 waves; wave w owns q-rows [w*16, w*16+16) across ALL 512 cols.
// T13 defer-max (THR=8): skip the 128-VALU acc rescale unless row max grows >8;
// P bounded by e^8 (bf16-safe, l in fp32). T5 setprio(1) around MFMA clusters.
__global__ __launch_bounds__(512, 2)
void attn_mfma(const unsigned short* __restrict__ Qc,   // [32768][320] hi|lo
               const unsigned short* __restrict__ Kc,   // [32768][320] hi|lo
               const unsigned short* __restrict__ VT,   // [8][512][4096] bf16
               float* __restrict__ O)                   // [32768][512] fp32
{
  // klds 32x328 (10496) + vtl 4x4112 (16448) + plds 8x(16x40) (5120) = 32064 ush = 64128 B
  __shared__ __align__(16) unsigned short smem[32064];
  unsigned short* klds = smem;              // 32 keys x 328 (320 data + 8 pad)
  unsigned short* vtl  = smem + 10496;      // 4 planes x [512 cols][8 keys]
  unsigned short* plds = smem + 26944;      // per-wave 16 rows x 40

  const int bid = blockIdx.x;
  const int b   = bid & 7;                  // XCD-affine batch
  const int qt  = bid >> 3;                 // 0..31
  const int r0  = (b << 12) + qt * 128;

  const int tid  = threadIdx.x;             // 0..511
  const int w    = tid >> 6;                // 0..7
  const int lane = tid & 63;
  const int quad = lane >> 4;
  const int cq   = lane & 15;

  // ---- persistent Q fragments (A-operand layout), rows r0 + w*16 + cq ----
  bf16x8 qhi[5], qlo[5];
  {
    const size_t qrow = (size_t)(r0 + w * 16 + cq) * 320;
#pragma unroll
    for (int c = 0; c < 5; ++c) {
      qhi[c] = u2b(*(const uint4*)(Qc + qrow + c * 32 + quad * 8));
      qlo[c] = u2b(*(const uint4*)(Qc + qrow + 160 + c * 32 + quad * 8));
    }
  }

  f32x4 acc4[32];
#pragma unroll
  for (int i = 0; i < 32; ++i) acc4[i] = (f32x4){0.f, 0.f, 0.f, 0.f};
  float mreg[4], lreg[4];
#pragma unroll
  for (int r = 0; r < 4; ++r) { mreg[r] = -3.0e38f; lreg[r] = 0.f; }

  const int vqd = (tid & 3) * 8;        // V key sub-offset (8 ushorts) = plane index *8
  const int vc  = tid >> 2;             // 0..127 column group
  const int vwb = (tid & 3) * 4112 + vc * 8;    // LDS write base (plane, col)
  const int vrb = quad * 4112 + cq * 8;          // LDS read base (+ i*128)

  // K staging geometry (1280 uint4 cells): p = tid, tid+512, (tid<256: tid+1024)
  const int krow0 = tid / 40,          kc0 = (tid - krow0 * 40) * 8;
  const int krow1 = (tid + 512) / 40,  kc1 = ((tid + 512) - krow1 * 40) * 8;
  const int krow2 = (tid + 1024) / 40, kc2 = ((tid + 1024) - krow2 * 40) * 8;

  uint4 pk0, pk1, pk2, pv0, pv1, pv2, pv3;
  // ---- initial prefetch (tile 0) ----
  const unsigned short* kbase = Kc + (size_t)(b * 4096) * 320;
  const unsigned short* vbase = VT + ((size_t)(b * 512 + vc)) * 4096 + vqd;
  {
    pk0 = *(const uint4*)(kbase + (size_t)tid * 8);
    pk1 = *(const uint4*)(kbase + (size_t)(tid + 512) * 8);
    if (tid < 256) pk2 = *(const uint4*)(kbase + (size_t)(tid + 1024) * 8);
    pv0 = *(const uint4*)(vbase);
    pv1 = *(const uint4*)(vbase + (size_t)128 * 4096);
    pv2 = *(const uint4*)(vbase + (size_t)256 * 4096);
    pv3 = *(const uint4*)(vbase + (size_t)384 * 4096);
  }

  for (int kt = 0; kt < 128; ++kt) {
    __syncthreads();  // A: previous tile's LDS readers done; drains prefetch loads

    // ---- stage prefetched K / V tiles into LDS ----
    *(uint4*)&klds[krow0 * 328 + kc0] = pk0;
    *(uint4*)&klds[krow1 * 328 + kc1] = pk1;
    if (tid < 256) *(uint4*)&klds[krow2 * 328 + kc2] = pk2;
    *(uint4*)&vtl[vwb]        = pv0;
    *(uint4*)&vtl[vwb + 1024] = pv1;
    *(uint4*)&vtl[vwb + 2048] = pv2;
    *(uint4*)&vtl[vwb + 3072] = pv3;

    __syncthreads();  // B: staging visible

    // ---- issue prefetch for next tile (in flight during S+softmax+PV) ----
    {
      const int ktn = (kt < 127) ? kt + 1 : 127;
      pk0 = *(const uint4*)(kbase + (size_t)(ktn * 32 * 320) + (size_t)tid * 8);
      pk1 = *(const uint4*)(kbase + (size_t)(ktn * 32 * 320) + (size_t)(tid + 512) * 8);
      if (tid < 256) pk2 = *(const uint4*)(kbase + (size_t)(ktn * 32 * 320) + (size_t)(tid + 1024) * 8);
      pv0 = *(const uint4*)(vbase + ktn * 32);
      pv1 = *(const uint4*)(vbase + (size_t)128 * 4096 + ktn * 32);
      pv2 = *(const uint4*)(vbase + (size_t)256 * 4096 + ktn * 32);
      pv3 = *(const uint4*)(vbase + (size_t)384 * 4096 + ktn * 32);
    }

    // ---- S phase: wave w -> rows [w*16, w*16+16) x 32 keys ----
    f32x4 S0 = (f32x4){0.f, 0.f, 0.f, 0.f};
    f32x4 S1 = (f32x4){0.f, 0.f, 0.f, 0.f};
    __builtin_amdgcn_s_setprio(1);
#pragma unroll
    for (int c = 0; c < 5; ++c) {
      const int ko = c * 32 + quad * 8;
      const bf16x8 kh0 = u2b(*(const uint4*)&klds[cq * 328 + ko]);
      const bf16x8 kl0 = u2b(*(const uint4*)&klds[cq * 328 + 160 + ko]);
      const bf16x8 kh1 = u2b(*(const uint4*)&klds[(16 + cq) * 328 + ko]);
      const bf16x8 kl1 = u2b(*(const uint4*)&klds[(16 + cq) * 328 + 160 + ko]);
      S0 = __builtin_amdgcn_mfma_f32_16x16x32_bf16(qhi[c], kh0, S0, 0, 0, 0);
      S1 = __builtin_amdgcn_mfma_f32_16x16x32_bf16(qhi[c], kh1, S1, 0, 0, 0);
      S0 = __builtin_amdgcn_mfma_f32_16x16x32_bf16(qhi[c], kl0, S0, 0, 0, 0);
      S1 = __builtin_amdgcn_mfma_f32_16x16x32_bf16(qhi[c], kl1, S1, 0, 0, 0);
      S0 = __builtin_amdgcn_mfma_f32_16x16x32_bf16(qlo[c], kh0, S0, 0, 0, 0);
      S1 = __builtin_amdgcn_mfma_f32_16x16x32_bf16(qlo[c], kh1, S1, 0, 0, 0);
    }
    __builtin_amdgcn_s_setprio(0);

    // ---- wave-local online softmax (row = quad*4+r, keys cq / 16+cq) ----
    // defer-max: keep old m unless the tile max exceeds it by >8 (P <= e^8)
    unsigned short* pw = plds + w * 640;
    float alph[4];
    bool upd = false;
#pragma unroll
    for (int r = 0; r < 4; ++r) {
      const float s0 = S0[r], s1 = S1[r];
      float t = fmaxf(s0, s1);
      t = fmaxf(t, __shfl_xor(t, 1));
      t = fmaxf(t, __shfl_xor(t, 2));
      t = fmaxf(t, __shfl_xor(t, 4));
      t = fmaxf(t, __shfl_xor(t, 8));
      const float mo = mreg[r];
      const bool need = (t > mo + 8.f);
      const float mn = need ? t : mo;
      upd = upd || need;
      const float al = need ? __expf(mo - mn) : 1.f;
      const float p0 = __expf(s0 - mn);
      const float p1 = __expf(s1 - mn);
      float ts = p0 + p1;
      ts += __shfl_xor(ts, 1);
      ts += __shfl_xor(ts, 2);
      ts += __shfl_xor(ts, 4);
      ts += __shfl_xor(ts, 8);
      lreg[r] = lreg[r] * al + ts;
      mreg[r] = mn;
      alph[r] = al;
      const int prow = (quad * 4 + r) * 40;
      pw[prow + cq]      = f2bf(p0);
      pw[prow + 16 + cq] = f2bf(p1);
    }

    if (__any(upd)) {
#pragma unroll
      for (int i = 0; i < 32; ++i) {
        acc4[i][0] *= alph[0]; acc4[i][1] *= alph[1];
        acc4[i][2] *= alph[2]; acc4[i][3] *= alph[3];
      }
    }

    // ---- PV phase (wave-local): rows [w*16..) x all 512 cols ----
    const bf16x8 pa = u2b(*(const uint4*)&pw[cq * 40 + quad * 8]);
    __builtin_amdgcn_s_setprio(1);
#pragma unroll
    for (int i = 0; i < 32; ++i) {
      const bf16x8 vb = u2b(*(const uint4*)&vtl[vrb + i * 128]);
      acc4[i] = __builtin_amdgcn_mfma_f32_16x16x32_bf16(pa, vb, acc4[i], 0, 0, 0);
    }
    __builtin_amdgcn_s_setprio(0);
  }

  // ---- epilogue: O = acc/l, staged through LDS (64-col eighths) ----
  float inv[4];
#pragma unroll
  for (int r = 0; r < 4; ++r) inv[r] = 1.f / lreg[r];

  __syncthreads();  // all waves done with klds/vtl before overlay
  float* ep = (float*)smem + w * 1088;     // 16 rows x 68 fp32 per wave (4352 B)
  const int r0w = r0 + w * 16;
#pragma unroll
  for (int qtr = 0; qtr < 8; ++qtr) {
#pragma unroll
    for (int ii = 0; ii < 4; ++ii)
#pragma unroll
      for (int r = 0; r < 4; ++r)
        ep[(quad * 4 + r) * 68 + ii * 16 + cq] = acc4[qtr * 4 + ii][r] * inv[r];
    // wave-private RAW; ds ops complete in order per wave
#pragma unroll
    for (int t = 0; t < 4; ++t) {
      const int flat4 = t * 64 + lane;     // 0..255 float4 units (16 rows x 16)
      const int row = flat4 >> 4;          // 0..15
      const int c4 = flat4 & 15;
      const float4 val = *(const float4*)&ep[row * 68 + c4 * 4];
      *(float4*)&O[(size_t)(r0w + row) * CDIM + qtr * 64 + c4 * 4] = val;
    }
  }
}

extern "C" void kernel_launch(void* const* d_in, const int* in_sizes, int n_in,
                              void* d_out, int out_size, void* d_ws, size_t ws_size,
                              hipStream_t stream)
{
  const float* x     = (const float*)d_in[0];
  const float* Wq    = (const float*)d_in[1];
  const float* bq    = (const float*)d_in[2];
  const float* Wk    = (const float*)d_in[3];
  const float* bk    = (const float*)d_in[4];
  const float* Wv    = (const float*)d_in[5];
  const float* bv    = (const float*)d_in[6];
  const float* Wres  = (const float*)d_in[7];
  const float* bres  = (const float*)d_in[8];
  const float* gamma = (const float*)d_in[9];

  float* seg_map  = (float*)d_out;                         // 32768 x 150
  float* feat_map = seg_map + (size_t)M_ROWS * KRANK;      // 32768 x 512

  unsigned short* Qcomb = (unsigned short*)d_ws;                       // [32768][320]
  unsigned short* Kcomb = Qcomb + (size_t)M_ROWS * 320;                // [32768][320]
  unsigned short* VTb   = Kcomb + (size_t)M_ROWS * 320;                // [8][512][4096]
  float*          feats = (float*)(VTb + (size_t)M_ROWS * CDIM);       // [32768][512]
  unsigned short* WvC   = (unsigned short*)(feats + (size_t)M_ROWS * CDIM); // 2x16 images
  unsigned short* WresC = WvC   + (size_t)2 * 16 * 16384;
  unsigned short* WqC   = WresC + (size_t)2 * 16 * 16384;              // 1x16 images
  unsigned short* WkC   = WqC   + (size_t)16 * 16384;

  cvt_w<<<dim3(96), dim3(512), 0, stream>>>(Wv, Wres, Wq, Wk, WvC, WresC, WqC, WkC);
  mgemm_nt<2><<<dim3(1, 256), dim3(512), 0, stream>>>(x, WqC, bq, seg_map, nullptr, nullptr, Qcomb);
  mgemm_nt<3><<<dim3(1, 256), dim3(512), 0, stream>>>(x, WkC, bk, nullptr, nullptr, nullptr, Kcomb);
  mgemm_nt<4><<<dim3(2, 256), dim3(512), 0, stream>>>(x, WvC, bv, nullptr, nullptr, nullptr, VTb);
  attn_mfma<<<dim3(256), dim3(512), 0, stream>>>(Qcomb, Kcomb, VTb, feats);
  mgemm_nt<1><<<dim3(2, 256), dim3(512), 0, stream>>>(feats, WresC, bres, feat_map, x, gamma, nullptr);
}

// Round 5
// 769.235 us; speedup vs baseline: 1.8563x; 1.0031x over previous
//
#include <hip/hip_runtime.h>
#include <cstdint>
#include <cstddef>

#define M_ROWS 32768   // B*N
#define CDIM   512
#define KRANK  150
#define KPAD   160     // padded rank for MFMA (zeros beyond 150)

typedef __bf16 bf16x8 __attribute__((ext_vector_type(8)));
typedef float  f32x4  __attribute__((ext_vector_type(4)));

union U16B { uint4 u; bf16x8 b; };
static __device__ __forceinline__ bf16x8 u2b(uint4 u) { U16B x; x.u = u; return x.b; }

static __device__ __forceinline__ unsigned short f2bf(float f) {
  uint32_t u = __float_as_uint(f);
  u += 0x7fffu + ((u >> 16) & 1u);
  return (unsigned short)(u >> 16);
}

// split 8 fp32 into hi/lo bf16 (hi = RNE(v), lo = RNE(v - hi)); err ~2^-16 rel
static __device__ __forceinline__ void cvt8(float4 a, float4 b, uint4& h, uint4& l) {
  float v[8] = {a.x, a.y, a.z, a.w, b.x, b.y, b.z, b.w};
  unsigned short hs[8], ls[8];
#pragma unroll
  for (int i = 0; i < 8; ++i) {
    hs[i] = f2bf(v[i]);
    const float hf = __uint_as_float((uint32_t)hs[i] << 16);
    ls[i] = f2bf(v[i] - hf);
  }
  h = *(uint4*)&hs[0];
  l = *(uint4*)&ls[0];
}

// async global->LDS, 16B per lane (dest = wave-uniform base + lane*16)
static __device__ __forceinline__ void glds16(const void* g, void* l) {
  __builtin_amdgcn_global_load_lds(
      (const __attribute__((address_space(1))) unsigned int*)g,
      (__attribute__((address_space(3))) unsigned int*)l, 16, 0, 0);
}

// swizzled 16B-cell index used by mgemm LDS tiles (row 0..127, k4 0..3)
static __device__ __forceinline__ int sa16f(int row, int k4) {
  return ((row >> 1) << 3) + ((((row & 1) << 2) | k4) ^ ((row >> 1) & 7));
}

// ============== W -> pre-swizzled hi/lo bf16 B-images ==============
// Image per (ntile, kt): 2048 cells x 16B = 32KB, laid out EXACTLY as mgemm's
// B LDS region: cells [0,1024) = BH (rows 0-127 at sa16, rows 128-255 at 512+sa16),
// cells [1024,2048) = BL. Rows >= N are zero (kills in-kernel masking).
// jobs: [Wv:32][Wres:32][Wq:16][Wk:16] = 96 blocks x 512 threads.
__global__ __launch_bounds__(512)
void cvt_w(const float* __restrict__ Wv, const float* __restrict__ Wres,
           const float* __restrict__ Wq, const float* __restrict__ Wk,
           unsigned short* __restrict__ WvC, unsigned short* __restrict__ WresC,
           unsigned short* __restrict__ WqC, unsigned short* __restrict__ WkC)
{
  int job = blockIdx.x;
  const float* W; unsigned short* img; int N;
  if (job < 32)      { W = Wv;   img = WvC;   N = 512; }
  else if (job < 64) { W = Wres; img = WresC; N = 512; job -= 32; }
  else if (job < 80) { W = Wq;   img = WqC;   N = KRANK; job -= 64; }
  else               { W = Wk;   img = WkC;   N = KRANK; job -= 80; }
  const int nt = (N == 512) ? (job >> 4) : 0;
  const int kt = job & 15;

  const int tid = threadIdx.x;
  const int srow = tid >> 2, sk4 = tid & 3;
  const int sa = sa16f(srow, sk4);
  unsigned short* ib = img + (size_t)(nt * 16 + kt) * 16384;  // 2048 cells * 8 ush
#pragma unroll
  for (int h = 0; h < 2; ++h) {
    const int row = nt * 256 + h * 128 + srow;
    float4 v0 = make_float4(0.f, 0.f, 0.f, 0.f), v1 = v0;
    if (row < N) {
      v0 = *(const float4*)&W[(size_t)row * 512 + kt * 32 + sk4 * 8];
      v1 = *(const float4*)&W[(size_t)row * 512 + kt * 32 + sk4 * 8 + 4];
    }
    uint4 h4, l4; cvt8(v0, v1, h4, l4);
    const int cell = h * 512 + sa;
    *(uint4*)&ib[(size_t)cell * 8]          = h4;
    *(uint4*)&ib[(size_t)(1024 + cell) * 8] = l4;
  }
}

// ================= MFMA hi/lo GEMM (fp32-accurate via 3-product bf16) =================
// out[m][n] = sum_k A[m][k]*W[n][k] (+bias).  M=32768, K=512.
// Tile: 128m x 256n per block, 8 waves (2m x 4n), wave tile 64x64 = 4x4 16x16 frags.
// A reg-staged + cvt8 (pair-swizzled cells); B staged via global_load_lds from the
// pre-swizzled Wimg (4 wave-instructions / K-step, async across barrier A->B).
// MODE 4: VT output bf16 [b][col][4096] (+bias).  MODE 1: out = gamma*(acc+bias)+xres.
// MODE 2: Q proj: fp32 out [m][150] + aux packed hi/lo [m][320]; grid x=1.
// MODE 3: K proj: aux only; grid x=1.
template<int MODE>
__global__ __launch_bounds__(512, 4)
void mgemm_nt(const float* __restrict__ A, const unsigned short* __restrict__ Wimg,
              const float* __restrict__ bias, float* __restrict__ out,
              const float* __restrict__ xres, const float* __restrict__ gammap,
              unsigned short* __restrict__ aux)
{
  // regions (ushort offsets): AH 0 (4096), AL 4096, BH 8192 (8192), BL 16384. 49152 B.
  __shared__ __align__(16) unsigned short lds[24576];
  const int tid = threadIdx.x;
  const int m0  = blockIdx.y * 128;

  // ---- A staging geometry: 512 cells (1/thread) ----
  const int srow = tid >> 2, sk4 = tid & 3;
  const int sa16 = sa16f(srow, sk4);
  const float* ap = A + (size_t)(m0 + srow) * 512 + sk4 * 8;

  // ---- fragment geometry ----
  const int lane = tid & 63, w = tid >> 6;
  const int wm = w >> 2, wn = w & 3;
  const int cq = lane & 15, quad = lane >> 4;
  const int fsub = (((cq & 1) << 2) | quad) ^ (cq >> 1);
  const int a16 = wm * 256 + ((cq >> 1) << 3) + fsub;   // + i*64 cells
  const int b16 = wn * 256 + ((cq >> 1) << 3) + fsub;   // + j*64 cells

  // B image base for this n-tile; per-lane src offset within each image
  const unsigned short* ibase = Wimg + (size_t)(blockIdx.x * 16) * 16384
                              + (size_t)(w * 64 + lane) * 8;

  f32x4 acc[4][4];
#pragma unroll
  for (int i = 0; i < 4; ++i)
#pragma unroll
    for (int j = 0; j < 4; ++j) acc[i][j] = (f32x4){0.f, 0.f, 0.f, 0.f};

  for (int kt = 0; kt < 512; kt += 32) {
    const float4 av0 = *(const float4*)(ap + kt);
    const float4 av1 = *(const float4*)(ap + kt + 4);
    uint4 ahi, alo;
    cvt8(av0, av1, ahi, alo);

    __syncthreads();   // A: previous tile's readers done
    *(uint4*)&lds[       sa16 * 8] = ahi;
    *(uint4*)&lds[4096 + sa16 * 8] = alo;
    const unsigned short* src = ibase + (size_t)(kt >> 5) * 16384;
#pragma unroll
    for (int c = 0; c < 4; ++c)
      glds16(src + (size_t)c * 4096, &lds[8192 + (c * 512 + w * 64) * 8]);
    __syncthreads();   // B: ds + vmem->lds drained, staging visible

    bf16x8 ah[4], al_[4];
#pragma unroll
    for (int i = 0; i < 4; ++i) {
      ah[i]  = u2b(*(const uint4*)&lds[       (a16 + i * 64) * 8]);
      al_[i] = u2b(*(const uint4*)&lds[4096 + (a16 + i * 64) * 8]);
    }
#pragma unroll
    for (int j = 0; j < 4; ++j) {
      const bf16x8 bh = u2b(*(const uint4*)&lds[8192  + (b16 + j * 64) * 8]);
      const bf16x8 bl = u2b(*(const uint4*)&lds[16384 + (b16 + j * 64) * 8]);
#pragma unroll
      for (int i = 0; i < 4; ++i) {
        acc[i][j] = __builtin_amdgcn_mfma_f32_16x16x32_bf16(ah[i],  bh, acc[i][j], 0, 0, 0);
        acc[i][j] = __builtin_amdgcn_mfma_f32_16x16x32_bf16(al_[i], bh, acc[i][j], 0, 0, 0);
        acc[i][j] = __builtin_amdgcn_mfma_f32_16x16x32_bf16(ah[i],  bl, acc[i][j], 0, 0, 0);
      }
    }
  }

  // ---- epilogue: C frag elem (i,j,r): m = m0+wm*64+i*16+quad*4+r, n = n0b+wn*64+j*16+cq
  const int n0b = blockIdx.x * 256;
  const int mb = m0 + wm * 64 + quad * 4;
  const int nb = n0b + wn * 64 + cq;

  if (MODE == 1) {
    const float g = gammap[0];
#pragma unroll
    for (int j = 0; j < 4; ++j) {
      const float bvj = bias[nb + j * 16];
#pragma unroll
      for (int i = 0; i < 4; ++i) {
#pragma unroll
        for (int r = 0; r < 4; ++r) {
          const size_t off = (size_t)(mb + i * 16 + r) * 512 + (nb + j * 16);
          out[off] = fmaf(g, acc[i][j][r] + bvj, xres[off]);
        }
      }
    }
  } else if (MODE == 4) {  // VT[b][n][key] bf16
    const int b = m0 >> 12;
    const int key0 = (m0 & 4095) + wm * 64 + quad * 4;
#pragma unroll
    for (int j = 0; j < 4; ++j) {
      const float bvj = bias[nb + j * 16];
      const size_t rowo = (size_t)(b * 512 + nb + j * 16) * 4096;
#pragma unroll
      for (int i = 0; i < 4; ++i) {
        unsigned short o4[4];
#pragma unroll
        for (int r = 0; r < 4; ++r) o4[r] = f2bf(acc[i][j][r] + bvj);
        uint2 o;
        o.x = (unsigned int)o4[0] | ((unsigned int)o4[1] << 16);
        o.y = (unsigned int)o4[2] | ((unsigned int)o4[3] << 16);
        *(uint2*)&aux[rowo + key0 + i * 16] = o;
      }
    }
  } else {  // MODE 2 / 3: Q/K projection outputs
#pragma unroll
    for (int j = 0; j < 4; ++j) {
      const int n = nb + j * 16;
      if (n < KPAD) {
        const float bvj = (n < KRANK) ? bias[n] : 0.f;
#pragma unroll
        for (int i = 0; i < 4; ++i) {
#pragma unroll
          for (int r = 0; r < 4; ++r) {
            const int m = mb + i * 16 + r;
            float v = (n < KRANK) ? (acc[i][j][r] + bvj) : 0.f;
            if (MODE == 2 && n < KRANK) out[(size_t)m * KRANK + n] = v;
            const unsigned short h = f2bf(v);
            aux[(size_t)m * 320 + n] = h;
            const float hf = __uint_as_float(((uint32_t)h) << 16);
            aux[(size_t)m * 320 + 160 + n] = f2bf(v - hf);
          }
        }
      }
    }
  }
}

// ================= MFMA flash attention (v9: shared-V PV + MFMA row-sums) =============
// 256 blocks: b = bid&7 (XCD-affine), qt = bid>>3. Block = 128 q-rows x 512 cols.
// S + softmax: wave w owns q-rows [w*16, w*16+16) (as before, Q in regs).
// PV: wave w (p=w>>1, h=w&1) owns row-tiles {2p,2p+1} x col-half h -> each V frag
// feeds 2 MFMAs (V LDS reads halved). Cross-wave P/alpha/l via LDS + 3rd barrier.
// Row-sums of P via ones-MFMA (matrix pipe) instead of 16 ds_swizzle (LDS pipe).
__global__ __launch_bounds__(512, 2)
void attn_mfma(const unsigned short* __restrict__ Qc,   // [32768][320] hi|lo
               const unsigned short* __restrict__ Kc,   // [32768][320] hi|lo
               const unsigned short* __restrict__ VT,   // [8][512][4096] bf16
               float* __restrict__ O)                   // [32768][512] fp32
{
  // klds 32x328 (10496) + vtl 4x4112 (16448) + plds 8x640 (5120) = 32064 ush
  // + alw 128 f32 (256) + updf 8 u32 (16) + linv 128 f32 (256) = 32592 ush = 65184 B
  __shared__ __align__(16) unsigned short smem[32592];
  unsigned short* klds = smem;              // 32 keys x 328 (320 data + 8 pad)
  unsigned short* vtl  = smem + 10496;      // 4 planes x [512 cols][8 keys]
  unsigned short* plds = smem + 26944;      // per-wave 16 rows x 40
  float*    alw   = (float*)(smem + 32064); // [wave][16 rows] rescale alpha
  unsigned* updf  = (unsigned*)(smem + 32320); // [wave] rescale flag
  float*    linvp = (float*)(smem + 32336); // [wave][16 rows] 1/l (epilogue)

  const int bid = blockIdx.x;
  const int b   = bid & 7;                  // XCD-affine batch
  const int qt  = bid >> 3;                 // 0..31
  const int r0  = (b << 12) + qt * 128;

  const int tid  = threadIdx.x;             // 0..511
  const int w    = tid >> 6;                // 0..7
  const int lane = tid & 63;
  const int quad = lane >> 4;
  const int cq   = lane & 15;
  const int p    = w >> 1;                  // PV row-pair
  const int h    = w & 1;                   // PV col-half

  // ---- persistent Q fragments (A-operand layout), rows r0 + w*16 + cq ----
  bf16x8 qhi[5], qlo[5];
  {
    const size_t qrow = (size_t)(r0 + w * 16 + cq) * 320;
#pragma unroll
    for (int c = 0; c < 5; ++c) {
      qhi[c] = u2b(*(const uint4*)(Qc + qrow + c * 32 + quad * 8));
      qlo[c] = u2b(*(const uint4*)(Qc + qrow + 160 + c * 32 + quad * 8));
    }
  }

  f32x4 acc4[32];   // [ct] = rows tile 2p, [16+ct] = rows tile 2p+1; cols h*256+ct*16
#pragma unroll
  for (int i = 0; i < 32; ++i) acc4[i] = (f32x4){0.f, 0.f, 0.f, 0.f};
  float mreg[4], lreg[4];
#pragma unroll
  for (int r = 0; r < 4; ++r) { mreg[r] = -3.0e38f; lreg[r] = 0.f; }

  const int vqd = (tid & 3) * 8;        // V key sub-offset (8 ushorts) = plane index *8
  const int vc  = tid >> 2;             // 0..127 column group
  const int vwb = (tid & 3) * 4112 + vc * 8;     // LDS write base (plane, col)
  const int vrb = quad * 4112 + h * 2048 + cq * 8;  // LDS read base (+ ct*128)

  // K staging geometry (1280 uint4 cells): p = tid, tid+512, (tid<256: tid+1024)
  const int krow0 = tid / 40,          kc0 = (tid - krow0 * 40) * 8;
  const int krow1 = (tid + 512) / 40,  kc1 = ((tid + 512) - krow1 * 40) * 8;
  const int krow2 = (tid + 1024) / 40, kc2 = ((tid + 1024) - krow2 * 40) * 8;

  uint4 os; os.x = os.y = os.z = os.w = 0x3F803F80u;   // bf16 1.0 x8
  const bf16x8 vone = u2b(os);

  uint4 pk0, pk1, pk2, pv0, pv1, pv2, pv3;
  // ---- initial prefetch (tile 0) ----
  const unsigned short* kbase = Kc + (size_t)(b * 4096) * 320;
  const unsigned short* vbase = VT + ((size_t)(b * 512 + vc)) * 4096 + vqd;
  {
    pk0 = *(const uint4*)(kbase + (size_t)tid * 8);
    pk1 = *(const uint4*)(kbase + (size_t)(tid + 512) * 8);
    if (tid < 256) pk2 = *(const uint4*)(kbase + (size_t)(tid + 1024) * 8);
    pv0 = *(const uint4*)(vbase);
    pv1 = *(const uint4*)(vbase + (size_t)128 * 4096);
    pv2 = *(const uint4*)(vbase + (size_t)256 * 4096);
    pv3 = *(const uint4*)(vbase + (size_t)384 * 4096);
  }

  for (int kt = 0; kt < 128; ++kt) {
    __syncthreads();  // A: previous tile's LDS readers done; drains prefetch loads

    // ---- stage prefetched K / V tiles into LDS ----
    *(uint4*)&klds[krow0 * 328 + kc0] = pk0;
    *(uint4*)&klds[krow1 * 328 + kc1] = pk1;
    if (tid < 256) *(uint4*)&klds[krow2 * 328 + kc2] = pk2;
    *(uint4*)&vtl[vwb]        = pv0;
    *(uint4*)&vtl[vwb + 1024] = pv1;
    *(uint4*)&vtl[vwb + 2048] = pv2;
    *(uint4*)&vtl[vwb + 3072] = pv3;

    __syncthreads();  // B: staging visible

    // ---- issue prefetch for next tile (in flight during S+softmax+PV) ----
    {
      const int ktn = (kt < 127) ? kt + 1 : 127;
      pk0 = *(const uint4*)(kbase + (size_t)(ktn * 32 * 320) + (size_t)tid * 8);
      pk1 = *(const uint4*)(kbase + (size_t)(ktn * 32 * 320) + (size_t)(tid + 512) * 8);
      if (tid < 256) pk2 = *(const uint4*)(kbase + (size_t)(ktn * 32 * 320) + (size_t)(tid + 1024) * 8);
      pv0 = *(const uint4*)(vbase + ktn * 32);
      pv1 = *(const uint4*)(vbase + (size_t)128 * 4096 + ktn * 32);
      pv2 = *(const uint4*)(vbase + (size_t)256 * 4096 + ktn * 32);
      pv3 = *(const uint4*)(vbase + (size_t)384 * 4096 + ktn * 32);
    }

    // ---- S phase: wave w -> rows [w*16, w*16+16) x 32 keys ----
    f32x4 S0 = (f32x4){0.f, 0.f, 0.f, 0.f};
    f32x4 S1 = (f32x4){0.f, 0.f, 0.f, 0.f};
    __builtin_amdgcn_s_setprio(1);
#pragma unroll
    for (int c = 0; c < 5; ++c) {
      const int ko = c * 32 + quad * 8;
      const bf16x8 kh0 = u2b(*(const uint4*)&klds[cq * 328 + ko]);
      const bf16x8 kl0 = u2b(*(const uint4*)&klds[cq * 328 + 160 + ko]);
      const bf16x8 kh1 = u2b(*(const uint4*)&klds[(16 + cq) * 328 + ko]);
      const bf16x8 kl1 = u2b(*(const uint4*)&klds[(16 + cq) * 328 + 160 + ko]);
      S0 = __builtin_amdgcn_mfma_f32_16x16x32_bf16(qhi[c], kh0, S0, 0, 0, 0);
      S1 = __builtin_amdgcn_mfma_f32_16x16x32_bf16(qhi[c], kh1, S1, 0, 0, 0);
      S0 = __builtin_amdgcn_mfma_f32_16x16x32_bf16(qhi[c], kl0, S0, 0, 0, 0);
      S1 = __builtin_amdgcn_mfma_f32_16x16x32_bf16(qhi[c], kl1, S1, 0, 0, 0);
      S0 = __builtin_amdgcn_mfma_f32_16x16x32_bf16(qlo[c], kh0, S0, 0, 0, 0);
      S1 = __builtin_amdgcn_mfma_f32_16x16x32_bf16(qlo[c], kh1, S1, 0, 0, 0);
    }
    __builtin_amdgcn_s_setprio(0);

    // ---- wave-local online softmax (row = quad*4+r, keys cq / 16+cq) ----
    // defer-max: keep old m unless tile max exceeds it by >8 (P <= e^8)
    unsigned short* pw = plds + w * 640;
    float alph[4];
    bool upd = false;
#pragma unroll
    for (int r = 0; r < 4; ++r) {
      const float s0 = S0[r], s1 = S1[r];
      float t = fmaxf(s0, s1);
      t = fmaxf(t, __shfl_xor(t, 1));
      t = fmaxf(t, __shfl_xor(t, 2));
      t = fmaxf(t, __shfl_xor(t, 4));
      t = fmaxf(t, __shfl_xor(t, 8));
      const float mo = mreg[r];
      const bool need = (t > mo + 8.f);
      const float mn = need ? t : mo;
      upd = upd || need;
      alph[r] = need ? __expf(mo - mn) : 1.f;
      mreg[r] = mn;
      const float p0 = __expf(s0 - mn);
      const float p1 = __expf(s1 - mn);
      const int prow = (quad * 4 + r) * 40;
      pw[prow + cq]      = f2bf(p0);
      pw[prow + 16 + cq] = f2bf(p1);
    }

    // ---- own-row sums via ones-MFMA (matrix pipe, replaces 16 ds_swizzle) ----
    {
      const bf16x8 pa_self = u2b(*(const uint4*)&pw[cq * 40 + quad * 8]);
      f32x4 sum4 = (f32x4){0.f, 0.f, 0.f, 0.f};
      sum4 = __builtin_amdgcn_mfma_f32_16x16x32_bf16(pa_self, vone, sum4, 0, 0, 0);
#pragma unroll
      for (int r = 0; r < 4; ++r) lreg[r] = lreg[r] * alph[r] + sum4[r];
    }
    if (cq == 0) {
#pragma unroll
      for (int r = 0; r < 4; ++r) alw[w * 16 + quad * 4 + r] = alph[r];
    }
    const bool anyu = __any(upd);
    if (lane == 0) updf[w] = anyu ? 1u : 0u;

    __syncthreads();  // C: P, alpha, upd flags visible to all waves

    // ---- PV phase: rows tiles {2p,2p+1} x cols [h*256, h*256+256) ----
    const unsigned short* pb = plds + (2 * p) * 640 + cq * 40 + quad * 8;
    const bf16x8 pa0 = u2b(*(const uint4*)pb);
    const bf16x8 pa1 = u2b(*(const uint4*)(pb + 640));

    if (updf[2 * p] | updf[2 * p + 1]) {   // rare under defer-max
      float aA[4], aB[4];
#pragma unroll
      for (int r = 0; r < 4; ++r) {
        aA[r] = alw[(2 * p) * 16 + quad * 4 + r];
        aB[r] = alw[(2 * p + 1) * 16 + quad * 4 + r];
      }
#pragma unroll
      for (int ct = 0; ct < 16; ++ct) {
#pragma unroll
        for (int r = 0; r < 4; ++r) {
          acc4[ct][r]      *= aA[r];
          acc4[16 + ct][r] *= aB[r];
        }
      }
    }

    __builtin_amdgcn_s_setprio(1);
#pragma unroll
    for (int ct = 0; ct < 16; ++ct) {
      const bf16x8 vb = u2b(*(const uint4*)&vtl[vrb + ct * 128]);
      acc4[ct]      = __builtin_amdgcn_mfma_f32_16x16x32_bf16(pa0, vb, acc4[ct], 0, 0, 0);
      acc4[16 + ct] = __builtin_amdgcn_mfma_f32_16x16x32_bf16(pa1, vb, acc4[16 + ct], 0, 0, 0);
    }
    __builtin_amdgcn_s_setprio(0);
  }

  // ---- epilogue: O = acc/l, cross-wave 1/l via LDS, staged through LDS ----
  if (cq == 0) {
#pragma unroll
    for (int r = 0; r < 4; ++r) linvp[w * 16 + quad * 4 + r] = 1.f / lreg[r];
  }
  __syncthreads();  // linv visible + all waves done with klds/vtl before overlay

  float invv[2][4];
#pragma unroll
  for (int rt = 0; rt < 2; ++rt)
#pragma unroll
    for (int r = 0; r < 4; ++r)
      invv[rt][r] = linvp[(2 * p + rt) * 16 + quad * 4 + r];

  float* ep = (float*)smem + w * 1088;     // 16 rows x 68 fp32 per wave (4352 B)
#pragma unroll
  for (int rt = 0; rt < 2; ++rt) {
    const int rowb = r0 + (2 * p + rt) * 16;
#pragma unroll
    for (int g = 0; g < 4; ++g) {
#pragma unroll
      for (int ii = 0; ii < 4; ++ii)
#pragma unroll
        for (int r = 0; r < 4; ++r)
          ep[(quad * 4 + r) * 68 + ii * 16 + cq] = acc4[rt * 16 + g * 4 + ii][r] * invv[rt][r];
      // wave-private RAW; ds ops complete in order per wave
#pragma unroll
      for (int t = 0; t < 4; ++t) {
        const int flat4 = t * 64 + lane;   // 0..255 float4 units (16 rows x 16)
        const int row = flat4 >> 4;        // 0..15
        const int c4 = flat4 & 15;
        const float4 val = *(const float4*)&ep[row * 68 + c4 * 4];
        *(float4*)&O[(size_t)(rowb + row) * CDIM + h * 256 + g * 64 + c4 * 4] = val;
      }
    }
  }
}

extern "C" void kernel_launch(void* const* d_in, const int* in_sizes, int n_in,
                              void* d_out, int out_size, void* d_ws, size_t ws_size,
                              hipStream_t stream)
{
  const float* x     = (const float*)d_in[0];
  const float* Wq    = (const float*)d_in[1];
  const float* bq    = (const float*)d_in[2];
  const float* Wk    = (const float*)d_in[3];
  const float* bk    = (const float*)d_in[4];
  const float* Wv    = (const float*)d_in[5];
  const float* bv    = (const float*)d_in[6];
  const float* Wres  = (const float*)d_in[7];
  const float* bres  = (const float*)d_in[8];
  const float* gamma = (const float*)d_in[9];

  float* seg_map  = (float*)d_out;                         // 32768 x 150
  float* feat_map = seg_map + (size_t)M_ROWS * KRANK;      // 32768 x 512

  unsigned short* Qcomb = (unsigned short*)d_ws;                       // [32768][320]
  unsigned short* Kcomb = Qcomb + (size_t)M_ROWS * 320;                // [32768][320]
  unsigned short* VTb   = Kcomb + (size_t)M_ROWS * 320;                // [8][512][4096]
  float*          feats = (float*)(VTb + (size_t)M_ROWS * CDIM);       // [32768][512]
  unsigned short* WvC   = (unsigned short*)(feats + (size_t)M_ROWS * CDIM); // 2x16 images
  unsigned short* WresC = WvC   + (size_t)2 * 16 * 16384;
  unsigned short* WqC   = WresC + (size_t)2 * 16 * 16384;              // 1x16 images
  unsigned short* WkC   = WqC   + (size_t)16 * 16384;

  cvt_w<<<dim3(96), dim3(512), 0, stream>>>(Wv, Wres, Wq, Wk, WvC, WresC, WqC, WkC);
  mgemm_nt<2><<<dim3(1, 256), dim3(512), 0, stream>>>(x, WqC, bq, seg_map, nullptr, nullptr, Qcomb);
  mgemm_nt<3><<<dim3(1, 256), dim3(512), 0, stream>>>(x, WkC, bk, nullptr, nullptr, nullptr, Kcomb);
  mgemm_nt<4><<<dim3(2, 256), dim3(512), 0, stream>>>(x, WvC, bv, nullptr, nullptr, nullptr, VTb);
  attn_mfma<<<dim3(256), dim3(512), 0, stream>>>(Qcomb, Kcomb, VTb, feats);
  mgemm_nt<1><<<dim3(2, 256), dim3(512), 0, stream>>>(feats, WresC, bres, feat_map, x, gamma, nullptr);
}